// Round 10
// baseline (653.682 us; speedup 1.0000x reference)
//
#include <hip/hip_runtime.h>

typedef unsigned short u16;
typedef __bf16 bf16x8 __attribute__((ext_vector_type(8)));
typedef __bf16 bf16x4 __attribute__((ext_vector_type(4)));
typedef float f32x4 __attribute__((ext_vector_type(4)));
typedef unsigned int u32x4 __attribute__((ext_vector_type(4)));

#define GLOAD_LDS16(g, l)                                                    \
  __builtin_amdgcn_global_load_lds(                                          \
      (const __attribute__((address_space(1))) void*)(g),                    \
      (__attribute__((address_space(3))) void*)(l), 16, 0, 0)

__device__ __forceinline__ u16 f2bf(float f) {
  unsigned int u = __float_as_uint(f);
  u += 0x7fffu + ((u >> 16) & 1u);   // RNE
  return (u16)(u >> 16);
}
__device__ __forceinline__ float bf2f(u16 h) {
  return __uint_as_float(((unsigned int)h) << 16);
}
// pack two f32 -> two bf16 (truncation) in one u32: low = a, high = b
// v_perm_b32: single-op, bit-identical to (b & 0xffff0000) | (a >> 16).
__device__ __forceinline__ unsigned int pack_bf2(float a, float b) {
#if __has_builtin(__builtin_amdgcn_perm)
  return __builtin_amdgcn_perm(__float_as_uint(b), __float_as_uint(a), 0x07060302u);
#else
  return (__float_as_uint(b) & 0xffff0000u) | (__float_as_uint(a) >> 16);
#endif
}
// raw v_exp_f32 — skips OCML denorm fixup. Safe: all inputs bounded (see call sites).
__device__ __forceinline__ float fexp2(float x) {
#if __has_builtin(__builtin_amdgcn_exp2f)
  return __builtin_amdgcn_exp2f(x);
#else
  return exp2f(x);
#endif
}
__device__ __forceinline__ float gelu_tanh(float x) {
  float u = 0.7978845608028654f * (x + 0.044715f * x * x * x);
  // exp(-2|u|) = 2^(-2*log2e*|u|); |u| bounded by gemm outputs -> no denorm concern
  float e = fexp2(-2.8853900817779268f * fabsf(u));
  float t = (1.0f - e) / (1.0f + e);
  t = (u >= 0.0f) ? t : -t;
  return 0.5f * x * (1.0f + t);
}
__device__ __forceinline__ float silu_f(float v) {
  return v / (1.0f + fexp2(-1.4426950408889634f * v));
}
__device__ __forceinline__ f32x4 mfma16(bf16x8 a, bf16x8 b, f32x4 c) {
  return __builtin_amdgcn_mfma_f32_16x16x32_bf16(a, b, c, 0, 0, 0);
}

// ---------------- modulation: out = silu(vec) @ W + b ----------------
__global__ __launch_bounds__(256) void modulation_kernel(
    const float* __restrict__ vec,
    const float* __restrict__ w_o, const float* __restrict__ b_o,
    const float* __restrict__ w_c, const float* __restrict__ b_c,
    float* __restrict__ o_mod, float* __restrict__ c_mod) {
  __shared__ float sv[1024];
  __shared__ float red[256];
  const int tid = threadIdx.x;
  const bool isobs = blockIdx.x < 96;
  const float* w = isobs ? w_o : w_c;
  const float* b = isobs ? b_o : b_c;
  float* out = isobs ? o_mod : c_mod;
  const int jb = (isobs ? blockIdx.x : blockIdx.x - 96) * 64;
  const int col = tid & 63, sl = tid >> 6;
  for (int i = tid; i < 1024; i += 256) {
    sv[i] = silu_f(vec[i]);
  }
  __syncthreads();
  float acc = 0.0f;
  const int kb = sl * 256;
  for (int k = 0; k < 256; ++k)
    acc += sv[kb + k] * w[(size_t)(kb + k) * 6144 + jb + col];
  red[tid] = acc;
  __syncthreads();
  if (sl == 0)
    out[jb + col] = red[col] + red[col + 64] + red[col + 128] + red[col + 192] + b[jb + col];
}

// ------------- LayerNorm + (1+scale)*y + shift -> bf16 ; rows: cond first -------------
__global__ __launch_bounds__(256) void ln_mod_kernel(
    const float* __restrict__ xc, const float* __restrict__ xo,
    const float* __restrict__ modc, const float* __restrict__ modo,
    int mod_off, u16* __restrict__ out) {
  const int row = blockIdx.x, tid = threadIdx.x;
  const bool is_c = row < 1024;
  const float* x = is_c ? (xc + (size_t)row * 1024) : (xo + (size_t)(row - 1024) * 1024);
  const float* mod = (is_c ? modc : modo) + mod_off;
  float4 v = *(const float4*)(x + tid * 4);
  float s1 = v.x + v.y + v.z + v.w;
  float s2 = v.x * v.x + v.y * v.y + v.z * v.z + v.w * v.w;
#pragma unroll
  for (int m = 1; m < 64; m <<= 1) {
    s1 += __shfl_xor(s1, m);
    s2 += __shfl_xor(s2, m);
  }
  __shared__ float red[8];
  const int w = tid >> 6;
  if ((tid & 63) == 0) { red[w] = s1; red[4 + w] = s2; }
  __syncthreads();
  s1 = red[0] + red[1] + red[2] + red[3];
  s2 = red[4] + red[5] + red[6] + red[7];
  const float mean = s1 * (1.0f / 1024.0f);
  const float var = s2 * (1.0f / 1024.0f) - mean * mean;
  const float rstd = rsqrtf(var + 1e-6f);
  const int d = tid * 4;
  float vv[4] = {v.x, v.y, v.z, v.w};
  ushort4 ov;
  u16* po = (u16*)&ov;
#pragma unroll
  for (int i = 0; i < 4; ++i) {
    float y = (vv[i] - mean) * rstd;
    po[i] = f2bf((1.0f + mod[1024 + d + i]) * y + mod[d + i]);
  }
  *(ushort4*)(out + (size_t)row * 1024 + d) = ov;
}

// ---- same, bf16 input (x1 residual stream) ----
__global__ __launch_bounds__(256) void ln_mod_b_kernel(
    const u16* __restrict__ x,
    const float* __restrict__ modc, const float* __restrict__ modo,
    int mod_off, u16* __restrict__ out) {
  const int row = blockIdx.x, tid = threadIdx.x;
  const bool is_c = row < 1024;
  const float* mod = (is_c ? modc : modo) + mod_off;
  ushort4 rv = *(const ushort4*)(x + (size_t)row * 1024 + tid * 4);
  float vv[4] = {bf2f(rv.x), bf2f(rv.y), bf2f(rv.z), bf2f(rv.w)};
  float s1 = vv[0] + vv[1] + vv[2] + vv[3];
  float s2 = vv[0] * vv[0] + vv[1] * vv[1] + vv[2] * vv[2] + vv[3] * vv[3];
#pragma unroll
  for (int m = 1; m < 64; m <<= 1) {
    s1 += __shfl_xor(s1, m);
    s2 += __shfl_xor(s2, m);
  }
  __shared__ float red[8];
  const int w = tid >> 6;
  if ((tid & 63) == 0) { red[w] = s1; red[4 + w] = s2; }
  __syncthreads();
  s1 = red[0] + red[1] + red[2] + red[3];
  s2 = red[4] + red[5] + red[6] + red[7];
  const float mean = s1 * (1.0f / 1024.0f);
  const float var = s2 * (1.0f / 1024.0f) - mean * mean;
  const float rstd = rsqrtf(var + 1e-6f);
  const int d = tid * 4;
  ushort4 ov;
  u16* po = (u16*)&ov;
#pragma unroll
  for (int i = 0; i < 4; ++i) {
    float y = (vv[i] - mean) * rstd;
    po[i] = f2bf((1.0f + mod[1024 + d + i]) * y + mod[d + i]);
  }
  *(ushort4*)(out + (size_t)row * 1024 + d) = ov;
}

// ---- weight pre-cast+transpose: src f32 [K][N] -> dst bf16 [N][K] ----
__global__ __launch_bounds__(256) void transcast_kernel(
    const float* __restrict__ src_c, const float* __restrict__ src_o,
    u16* __restrict__ dst_c, u16* __restrict__ dst_o, int K, int N) {
  const float* src = blockIdx.z ? src_o : src_c;
  u16* dst = blockIdx.z ? dst_o : dst_c;
  const int n0 = blockIdx.x * 64, k0 = blockIdx.y * 64;
  __shared__ float s[64][65];
  const int tid = threadIdx.x;
  const int r = tid >> 4, c4 = (tid & 15) << 2;
#pragma unroll
  for (int p = 0; p < 4; ++p) {
    int kk = r + p * 16;
    float4 v = *(const float4*)(src + (size_t)(k0 + kk) * N + n0 + c4);
    s[kk][c4] = v.x; s[kk][c4 + 1] = v.y; s[kk][c4 + 2] = v.z; s[kk][c4 + 3] = v.w;
  }
  __syncthreads();
#pragma unroll
  for (int p = 0; p < 4; ++p) {
    int nr = r + p * 16;
    ushort4 ov;
    ov.x = f2bf(s[c4 + 0][nr]); ov.y = f2bf(s[c4 + 1][nr]);
    ov.z = f2bf(s[c4 + 2][nr]); ov.w = f2bf(s[c4 + 3][nr]);
    *(ushort4*)(dst + (size_t)(n0 + nr) * K + k0 + c4) = ov;
  }
}

// ---------------- GEMM m97-style: A bf16 [M][K] x BT bf16 [N][K], 128xBNx32 ----------------
// mode 0 epilogue writes V directly in vpack fragment layout (vtrans folded in).
template <int BN>
__global__ __launch_bounds__(256) void gemm_bf16(
    const u16* __restrict__ A, const u16* __restrict__ BTc, const u16* __restrict__ BTo,
    int N, int K, int mode,
    const float* __restrict__ bias_c, const float* __restrict__ bias_o,
    const float* __restrict__ gate_c, const float* __restrict__ gate_o,
    const float* __restrict__ x0_c, const float* __restrict__ x0_o,
    const u16* __restrict__ x1, void* __restrict__ outp,
    u16* __restrict__ oq, u16* __restrict__ ok, u16* __restrict__ ov) {
  constexpr int MI = (BN == 128) ? 4 : 2;
  __shared__ u16 As[128 * 32];   // unpadded: global_load_lds is lane-linear
  __shared__ u16 Bs[BN * 32];
  const int tid = threadIdx.x;
  const int m0 = blockIdx.y * 128, n0 = blockIdx.x * BN;
  const bool is_c = (m0 < 1024);
  const u16* __restrict__ BT = is_c ? BTc : BTo;
  const int w = tid >> 6, lane = tid & 63, quad = lane >> 4, ln = lane & 15;
  const int wm = (BN == 128) ? (w >> 1) * 64 : w * 32;
  const int wn = (BN == 128) ? (w & 1) * 64 : 0;
  f32x4 acc[MI][4] = {};
  const int nkt = K >> 5;
  for (int kt = 0; kt < nkt; ++kt) {
    __syncthreads();
    {
      int c = tid;
      GLOAD_LDS16(A + (size_t)(m0 + (c >> 2)) * K + kt * 32 + (c & 3) * 8, As + c * 8);
      c = tid + 256;
      GLOAD_LDS16(A + (size_t)(m0 + (c >> 2)) * K + kt * 32 + (c & 3) * 8, As + c * 8);
      c = tid;
      GLOAD_LDS16(BT + (size_t)(n0 + (c >> 2)) * K + kt * 32 + (c & 3) * 8, Bs + c * 8);
      if (BN == 128) {
        c = tid + 256;
        GLOAD_LDS16(BT + (size_t)(n0 + (c >> 2)) * K + kt * 32 + (c & 3) * 8, Bs + c * 8);
      }
    }
    __syncthreads();
    bf16x8 a[MI], b[4];
#pragma unroll
    for (int i = 0; i < MI; ++i)
      a[i] = *(const bf16x8*)(As + (wm + i * 16 + ln) * 32 + quad * 8);
#pragma unroll
    for (int j = 0; j < 4; ++j)
      b[j] = *(const bf16x8*)(Bs + (wn + j * 16 + ln) * 32 + quad * 8);
#pragma unroll
    for (int i = 0; i < MI; ++i)
#pragma unroll
      for (int j = 0; j < 4; ++j) acc[i][j] = mfma16(a[i], b[j], acc[i][j]);
  }
  const float* bias = is_c ? bias_c : bias_o;
  const float* gate = is_c ? gate_c : gate_o;
  const float* x0 = is_c ? x0_c : x0_o;
#pragma unroll
  for (int i = 0; i < MI; ++i) {
#pragma unroll
    for (int j = 0; j < 4; ++j) {
#pragma unroll
      for (int r = 0; r < 4; ++r) {
        const int row = m0 + wm + i * 16 + quad * 4 + r;
        const int col = n0 + wn + j * 16 + ln;
        const float v = acc[i][j][r];
        if (mode == 0) {
          const int which = col >> 10, hh = (col & 1023) >> 6, dd = col & 63;
          if (which == 2) {
            // V: straight to vpack fragment layout (see vpack comment at qkprep)
            const int cc = row >> 7, wv = (row >> 5) & 3, qd = (row >> 3) & 3, jr = row & 7;
            const int jd = dd >> 4, lnn = dd & 15;
            ov[(size_t)hh * 262144 +
               (size_t)(((((cc * 4 + wv) * 4 + jd) * 64) + qd * 16 + lnn) * 8 + jr)] = f2bf(v);
          } else {
            u16* dst = (which == 0) ? oq : ok;
            dst[((size_t)hh * 4096 + row) * 64 + dd] = f2bf(v);
          }
        } else if (mode == 1) {
          const float xv = is_c ? x0[(size_t)row * 1024 + col]
                                : x0[(size_t)(row - 1024) * 1024 + col];
          ((u16*)outp)[(size_t)row * 1024 + col] = f2bf(xv + gate[col] * (v + bias[col]));
        } else if (mode == 2) {
          ((u16*)outp)[(size_t)row * N + col] = f2bf(gelu_tanh(v + bias[col]));
        } else {
          const float res = bf2f(x1[(size_t)row * 1024 + col]);
          const float val = res + gate[col] * (v + bias[col]);
          const size_t oidx = (row < 1024)
              ? (size_t)3145728 + (size_t)row * 1024 + col
              : (size_t)(row - 1024) * 1024 + col;
          ((float*)outp)[oidx] = val;
        }
      }
    }
  }
}

// ---- in-place rmsnorm+rope on q; k additionally scattered to fragment-packed kpack ----
// kpack layout (per head, u16 units): unit = ((c*4 + w)*4 + kk*2 + hf); element
// [unit*512 + (quad*16+ln)*8 + j] = K[l = c*128 + w*32 + (ln>>2)*8 + kk*4 + (ln&3)]
//                                    [d = hf*32 + quad*8 + j]
// vpack layout (per head, u16 units): unit = ((c*4 + w)*4 + jd); element
// [unit*512 + (quad*16+ln)*8 + j] = V[key = c*128 + w*32 + quad*8 + j][d = jd*16 + ln]
// so attn's fragment loads are single coalesced lane-linear 1KB streams.
__global__ __launch_bounds__(256) void qkprep_kernel(
    const float* __restrict__ pe,
    const float* __restrict__ qs_c, const float* __restrict__ ks_c,
    const float* __restrict__ qs_o, const float* __restrict__ ks_o,
    u16* __restrict__ qraw, u16* __restrict__ kraw, u16* __restrict__ kpack) {
  const int l = blockIdx.x, tid = threadIdx.x;
  const bool is_c = l < 1024;
  const float* qs = is_c ? qs_c : qs_o;
  const float* ks = is_c ? ks_c : ks_o;
  const int head = tid >> 4, dd = (tid * 4) & 63;
  const size_t off = ((size_t)head * 4096 + l) * 64 + dd;
  const float* peb = pe + (size_t)l * 128 + (size_t)dd * 2;
  float4 pe0 = *(const float4*)(peb);
  float4 pe1 = *(const float4*)(peb + 4);
  {  // q (scaled into exp2-score domain), in-place
    ushort4 raw = *(const ushort4*)(qraw + off);
    float x0 = bf2f(raw.x), x1v = bf2f(raw.y), x2 = bf2f(raw.z), x3 = bf2f(raw.w);
    float ssq = x0 * x0 + x1v * x1v + x2 * x2 + x3 * x3;
#pragma unroll
    for (int m = 1; m < 16; m <<= 1) ssq += __shfl_xor(ssq, m);
    float rms = rsqrtf(ssq * (1.0f / 64.0f) + 1e-6f) * 0.18033688011112042f;
    float n0 = x0 * rms * qs[dd + 0], n1 = x1v * rms * qs[dd + 1];
    float n2 = x2 * rms * qs[dd + 2], n3 = x3 * rms * qs[dd + 3];
    ushort4 o;
    o.x = f2bf(pe0.x * n0 + pe0.y * n1);
    o.y = f2bf(pe0.z * n0 + pe0.w * n1);
    o.z = f2bf(pe1.x * n2 + pe1.y * n3);
    o.w = f2bf(pe1.z * n2 + pe1.w * n3);
    *(ushort4*)(qraw + off) = o;
  }
  {  // k -> fragment-packed kpack
    ushort4 raw = *(const ushort4*)(kraw + off);
    float x0 = bf2f(raw.x), x1v = bf2f(raw.y), x2 = bf2f(raw.z), x3 = bf2f(raw.w);
    float ssq = x0 * x0 + x1v * x1v + x2 * x2 + x3 * x3;
#pragma unroll
    for (int m = 1; m < 16; m <<= 1) ssq += __shfl_xor(ssq, m);
    float rms = rsqrtf(ssq * (1.0f / 64.0f) + 1e-6f);
    float n0 = x0 * rms * ks[dd + 0], n1 = x1v * rms * ks[dd + 1];
    float n2 = x2 * rms * ks[dd + 2], n3 = x3 * rms * ks[dd + 3];
    ushort4 o;
    o.x = f2bf(pe0.x * n0 + pe0.y * n1);
    o.y = f2bf(pe0.z * n0 + pe0.w * n1);
    o.z = f2bf(pe1.x * n2 + pe1.y * n3);
    o.w = f2bf(pe1.z * n2 + pe1.w * n3);
    const int cck = l >> 7, wvk = (l >> 5) & 3, rk = l & 31;
    const int kkk = (rk >> 2) & 1, lnk = ((rk >> 3) << 2) | (rk & 3);
    const int hfk = dd >> 5, qdk = (dd >> 3) & 3, j0k = dd & 7;
    u16* kdst = kpack + (size_t)head * 262144
        + (size_t)((((cck * 4 + wvk) * 4 + kkk * 2 + hfk) * 64 + qdk * 16 + lnk) * 8 + j0k);
    *(ushort4*)kdst = o;
  }
}

// ---- one pipelined chunk: coalesced fragment-stream prefetch, QK -> exp2 -> PV ----
// K fragments pre-permuted (kperm baked into kpack) so sT[kk][nq][r] at lane
// (quad,ln) holds P[nq*16+ln][key quad*8+kk*4+r]: the exact 8 keys PV's A-operand
// needs, in-lane. P never touches LDS; loads are lane-linear 1KB streams.
__device__ __forceinline__ void attn_chunk(
    int cn, const u16* kpB, const u16* vpB, int w, int lane,
    const bf16x8 (&bq)[4][2],
    bf16x8 (&akc)[2][2], bf16x8 (&bvc)[4],
    bf16x8 (&akn)[2][2], bf16x8 (&bvn)[4],
    f32x4 (&o)[4][4], float (&rs)[4]) {
  if (cn < 32) {   // prefetch chunk cn into the other buffer (covers ~1 chunk of compute)
    const int cb = (cn * 4 + w) * 4;
#pragma unroll
    for (int kk = 0; kk < 2; ++kk)
#pragma unroll
      for (int hf = 0; hf < 2; ++hf)
        akn[kk][hf] = *(const bf16x8*)(kpB + ((cb + kk * 2 + hf) << 9) + lane * 8);
#pragma unroll
    for (int jd = 0; jd < 4; ++jd)
      bvn[jd] = *(const bf16x8*)(vpB + ((cb + jd) << 9) + lane * 8);
  }
  f32x4 sT[2][4] = {};
#pragma unroll
  for (int kk = 0; kk < 2; ++kk)
#pragma unroll
    for (int nq = 0; nq < 4; ++nq) {
      sT[kk][nq] = mfma16(akc[kk][0], bq[nq][0], sT[kk][nq]);
      sT[kk][nq] = mfma16(akc[kk][1], bq[nq][1], sT[kk][nq]);
    }
  // raw v_exp_f32: scores pre-scaled by 0.125*log2e and bounded => no fixup needed
#pragma unroll
  for (int nq = 0; nq < 4; ++nq) {
    u32x4 pw;
#pragma unroll
    for (int kk = 0; kk < 2; ++kk) {
      float p0 = fexp2(sT[kk][nq][0]);
      float p1 = fexp2(sT[kk][nq][1]);
      float p2 = fexp2(sT[kk][nq][2]);
      float p3 = fexp2(sT[kk][nq][3]);
      rs[nq] += (p0 + p1) + (p2 + p3);
      pw[kk * 2 + 0] = pack_bf2(p0, p1);
      pw[kk * 2 + 1] = pack_bf2(p2, p3);
    }
    const bf16x8 ap = __builtin_bit_cast(bf16x8, pw);
#pragma unroll
    for (int jd = 0; jd < 4; ++jd)
      o[nq][jd] = mfma16(ap, bvc[jd], o[nq][jd]);
  }
}

// ------- flash attention v11: packed streams, LDS-free P, XCD head clustering -------
__global__ __launch_bounds__(256) void attn_kernel(
    const u16* __restrict__ qh, const u16* __restrict__ kp,
    const u16* __restrict__ vp, u16* __restrict__ attn) {
  constexpr int L = 4096;
  // XCD-aware remap: linear block L0 dispatches to XCD (L0 % 8). Give each head's
  // 64 blocks a fixed L0%8 so its 1MB kpack+vpack stays resident in ONE XCD's L2
  // (2 heads/XCD = 2MB < 4MiB). Measured: FETCH 69.7->12.4 MB (R9).
  const int L0 = blockIdx.y * 64 + blockIdx.x;
  const int h = (L0 & 7) * 2 + ((L0 >> 3) & 1);
  const int q0 = (L0 >> 4) * 64;
  const int tid = threadIdx.x, w = tid >> 6, lane = tid & 63;
  const int quad = lane >> 4, ln = lane & 15;
  // LDS used only by the epilogue cross-wave reduction (bufA/bufB/rs4)
  __shared__ __align__(16) char smem[35840];
  float* bufA = (float*)smem;
  float* bufB = bufA + 4352;
  float* rs4 = bufB + 4352;

  bf16x8 bq[4][2];
  const u16* qbase = qh + ((size_t)h * L + q0) * 64;
#pragma unroll
  for (int nq = 0; nq < 4; ++nq)
#pragma unroll
    for (int hf = 0; hf < 2; ++hf)
      bq[nq][hf] = *(const bf16x8*)(qbase + (nq * 16 + ln) * 64 + hf * 32 + quad * 8);

  f32x4 o[4][4] = {};
  float rs[4] = {0.f, 0.f, 0.f, 0.f};
  const u16* kpB = kp + (size_t)h * 262144;
  const u16* vpB = vp + (size_t)h * 262144;

  // double-buffered K/V register fragments; ping-pong via 2-unrolled loop
  bf16x8 akA[2][2], akB[2][2], bvA[4], bvB[4];
  {
    const int cb = w * 4;
#pragma unroll
    for (int kk = 0; kk < 2; ++kk)
#pragma unroll
      for (int hf = 0; hf < 2; ++hf)
        akA[kk][hf] = *(const bf16x8*)(kpB + ((cb + kk * 2 + hf) << 9) + lane * 8);
#pragma unroll
    for (int jd = 0; jd < 4; ++jd)
      bvA[jd] = *(const bf16x8*)(vpB + ((cb + jd) << 9) + lane * 8);
  }
  for (int c = 0; c < 32; c += 2) {
    attn_chunk(c + 1, kpB, vpB, w, lane, bq, akA, bvA, akB, bvB, o, rs);
    attn_chunk(c + 2, kpB, vpB, w, lane, bq, akB, bvB, akA, bvA, o, rs);
  }

  // ---- epilogue: cross-wave reduction of o and rs ----
  __syncthreads();
#pragma unroll
  for (int nq = 0; nq < 4; ++nq) {
    rs[nq] += __shfl_xor(rs[nq], 16);
    rs[nq] += __shfl_xor(rs[nq], 32);
  }
  if (quad == 0) {
#pragma unroll
    for (int nq = 0; nq < 4; ++nq) rs4[w * 64 + nq * 16 + ln] = rs[nq];
  }
  if (w == 1) {
#pragma unroll
    for (int nq = 0; nq < 4; ++nq)
#pragma unroll
      for (int jd = 0; jd < 4; ++jd)
        *(f32x4*)(bufA + (jd * 16 + ln) * 68 + nq * 16 + quad * 4) = o[nq][jd];
  }
  if (w == 3) {
#pragma unroll
    for (int nq = 0; nq < 4; ++nq)
#pragma unroll
      for (int jd = 0; jd < 4; ++jd)
        *(f32x4*)(bufB + (jd * 16 + ln) * 68 + nq * 16 + quad * 4) = o[nq][jd];
  }
  __syncthreads();
  if (w == 0) {
#pragma unroll
    for (int nq = 0; nq < 4; ++nq)
#pragma unroll
      for (int jd = 0; jd < 4; ++jd)
        o[nq][jd] += *(const f32x4*)(bufA + (jd * 16 + ln) * 68 + nq * 16 + quad * 4);
  }
  if (w == 2) {
#pragma unroll
    for (int nq = 0; nq < 4; ++nq)
#pragma unroll
      for (int jd = 0; jd < 4; ++jd)
        o[nq][jd] += *(const f32x4*)(bufB + (jd * 16 + ln) * 68 + nq * 16 + quad * 4);
  }
  __syncthreads();
  if (w == 2) {
#pragma unroll
    for (int nq = 0; nq < 4; ++nq)
#pragma unroll
      for (int jd = 0; jd < 4; ++jd)
        *(f32x4*)(bufA + (jd * 16 + ln) * 68 + nq * 16 + quad * 4) = o[nq][jd];
  }
  __syncthreads();
  if (w == 0) {
    float linv[4][4];
#pragma unroll
    for (int nq = 0; nq < 4; ++nq)
#pragma unroll
      for (int r = 0; r < 4; ++r) {
        const int qr = nq * 16 + quad * 4 + r;
        linv[nq][r] = 1.0f / (rs4[qr] + rs4[64 + qr] + rs4[128 + qr] + rs4[192 + qr]);
      }
#pragma unroll
    for (int nq = 0; nq < 4; ++nq)
#pragma unroll
      for (int jd = 0; jd < 4; ++jd) {
        f32x4 of = o[nq][jd];
        of += *(const f32x4*)(bufA + (jd * 16 + ln) * 68 + nq * 16 + quad * 4);
#pragma unroll
        for (int r = 0; r < 4; ++r) {
          const int row = q0 + nq * 16 + quad * 4 + r;
          attn[(size_t)row * 1024 + h * 64 + jd * 16 + ln] = f2bf(of[r] * linv[nq][r]);
        }
      }
  }
}

extern "C" void kernel_launch(void* const* d_in, const int* in_sizes, int n_in,
                              void* d_out, int out_size, void* d_ws, size_t ws_size,
                              hipStream_t stream) {
  (void)in_sizes; (void)n_in; (void)out_size; (void)ws_size;
  const float* obs         = (const float*)d_in[0];
  const float* cond        = (const float*)d_in[1];
  const float* vec         = (const float*)d_in[2];
  const float* pe          = (const float*)d_in[3];
  const float* obs_mod_w   = (const float*)d_in[4];
  const float* obs_mod_b   = (const float*)d_in[5];
  const float* obs_qkv_w   = (const float*)d_in[6];
  const float* obs_q_scale = (const float*)d_in[7];
  const float* obs_k_scale = (const float*)d_in[8];
  const float* obs_proj_w  = (const float*)d_in[9];
  const float* obs_proj_b  = (const float*)d_in[10];
  const float* obs_mlp_w1  = (const float*)d_in[11];
  const float* obs_mlp_b1  = (const float*)d_in[12];
  const float* obs_mlp_w2  = (const float*)d_in[13];
  const float* obs_mlp_b2  = (const float*)d_in[14];
  const float* cond_mod_w  = (const float*)d_in[15];
  const float* cond_mod_b  = (const float*)d_in[16];
  const float* cond_qkv_w  = (const float*)d_in[17];
  const float* cond_q_scale= (const float*)d_in[18];
  const float* cond_k_scale= (const float*)d_in[19];
  const float* cond_proj_w = (const float*)d_in[20];
  const float* cond_proj_b = (const float*)d_in[21];
  const float* cond_mlp_w1 = (const float*)d_in[22];
  const float* cond_mlp_b1 = (const float*)d_in[23];
  const float* cond_mlp_w2 = (const float*)d_in[24];
  const float* cond_mlp_b2 = (const float*)d_in[25];

  // Workspace (peak 64 MiB + 64 KiB — proven budget):
  //  [0,16M)   rotating bf16 weights: qkvT -> projT -> mlp1T -> mlp2T
  //  [16,24M)  xm -> x1(bf16)
  //  [24,32M)  qraw -> hm
  //  [32,40M)  kraw ─┐
  //  [40,48M)  kpack (ex-vraw slot; V now packed by gemm)  ├─> g (32 MiB after dead)
  //  [48,56M)  vpack ─┤
  //  [56,64M)  attn  ─┘
  char* ws = (char*)d_ws;
  float* o_mod = (float*)ws;
  float* c_mod = o_mod + 6144;
  char* base = ws + 65536;
  u16* qkvT_c  = (u16*)base;
  u16* qkvT_o  = (u16*)(base + 6291456);
  u16* projT_c = (u16*)base;
  u16* projT_o = (u16*)(base + 2097152);
  u16* mlp1T_c = (u16*)base;
  u16* mlp1T_o = (u16*)(base + 8388608);
  u16* mlp2T_c = (u16*)base;
  u16* mlp2T_o = (u16*)(base + 8388608);
  u16* xm   = (u16*)(base + 16777216);
  u16* x1   = (u16*)(base + 16777216);
  u16* qraw = (u16*)(base + 25165824);
  u16* hm   = (u16*)(base + 25165824);
  u16* kraw = (u16*)(base + 33554432);
  u16* kpack= (u16*)(base + 41943040);
  u16* vpack= (u16*)(base + 50331648);
  u16* attn = (u16*)(base + 58720256);
  u16* g    = (u16*)(base + 33554432);

  modulation_kernel<<<192, 256, 0, stream>>>(vec, obs_mod_w, obs_mod_b,
                                             cond_mod_w, cond_mod_b, o_mod, c_mod);
  ln_mod_kernel<<<4096, 256, 0, stream>>>(cond, obs, c_mod, o_mod, 0, xm);
  transcast_kernel<<<dim3(48, 16, 2), 256, 0, stream>>>(cond_qkv_w, obs_qkv_w,
                                                        qkvT_c, qkvT_o, 1024, 3072);
  gemm_bf16<128><<<dim3(24, 32), 256, 0, stream>>>(xm, qkvT_c, qkvT_o, 3072, 1024, 0,
      nullptr, nullptr, nullptr, nullptr, nullptr, nullptr, nullptr, nullptr,
      qraw, kraw, vpack);   // V written directly in vpack layout (vtrans folded)
  qkprep_kernel<<<4096, 256, 0, stream>>>(pe, cond_q_scale, cond_k_scale,
                                          obs_q_scale, obs_k_scale, qraw, kraw, kpack);
  attn_kernel<<<dim3(64, 16), 256, 0, stream>>>(qraw, kpack, vpack, attn);
  transcast_kernel<<<dim3(16, 16, 2), 256, 0, stream>>>(cond_proj_w, obs_proj_w,
                                                        projT_c, projT_o, 1024, 1024);
  gemm_bf16<64><<<dim3(16, 32), 256, 0, stream>>>(attn, projT_c, projT_o, 1024, 1024, 1,
      cond_proj_b, obs_proj_b, c_mod + 2048, o_mod + 2048, cond, obs,
      nullptr, (void*)x1, nullptr, nullptr, nullptr);
  ln_mod_b_kernel<<<4096, 256, 0, stream>>>(x1, c_mod, o_mod, 3072, hm);
  transcast_kernel<<<dim3(64, 16, 2), 256, 0, stream>>>(cond_mlp_w1, obs_mlp_w1,
                                                        mlp1T_c, mlp1T_o, 1024, 4096);
  gemm_bf16<128><<<dim3(32, 32), 256, 0, stream>>>(hm, mlp1T_c, mlp1T_o, 4096, 1024, 2,
      cond_mlp_b1, obs_mlp_b1, nullptr, nullptr, nullptr, nullptr,
      nullptr, (void*)g, nullptr, nullptr, nullptr);
  transcast_kernel<<<dim3(16, 64, 2), 256, 0, stream>>>(cond_mlp_w2, obs_mlp_w2,
                                                        mlp2T_c, mlp2T_o, 4096, 1024);
  gemm_bf16<128><<<dim3(8, 32), 256, 0, stream>>>(g, mlp2T_c, mlp2T_o, 1024, 4096, 3,
      cond_mlp_b2, obs_mlp_b2, c_mod + 5120, o_mod + 5120, nullptr, nullptr,
      x1, d_out, nullptr, nullptr, nullptr);
}

// Round 11
// 641.238 us; speedup vs baseline: 1.0194x; 1.0194x over previous
//
#include <hip/hip_runtime.h>

typedef unsigned short u16;
typedef __bf16 bf16x8 __attribute__((ext_vector_type(8)));
typedef __bf16 bf16x4 __attribute__((ext_vector_type(4)));
typedef float f32x4 __attribute__((ext_vector_type(4)));
typedef unsigned int u32x4 __attribute__((ext_vector_type(4)));

#define GLOAD_LDS16(g, l)                                                    \
  __builtin_amdgcn_global_load_lds(                                          \
      (const __attribute__((address_space(1))) void*)(g),                    \
      (__attribute__((address_space(3))) void*)(l), 16, 0, 0)

__device__ __forceinline__ u16 f2bf(float f) {
  unsigned int u = __float_as_uint(f);
  u += 0x7fffu + ((u >> 16) & 1u);   // RNE
  return (u16)(u >> 16);
}
__device__ __forceinline__ float bf2f(u16 h) {
  return __uint_as_float(((unsigned int)h) << 16);
}
// pack two f32 -> two bf16 (truncation) in one u32: low = a, high = b
// v_perm_b32: single-op, bit-identical to (b & 0xffff0000) | (a >> 16).
__device__ __forceinline__ unsigned int pack_bf2(float a, float b) {
#if __has_builtin(__builtin_amdgcn_perm)
  return __builtin_amdgcn_perm(__float_as_uint(b), __float_as_uint(a), 0x07060302u);
#else
  return (__float_as_uint(b) & 0xffff0000u) | (__float_as_uint(a) >> 16);
#endif
}
// raw v_exp_f32 — skips OCML denorm fixup. Safe: all inputs bounded (see call sites).
__device__ __forceinline__ float fexp2(float x) {
#if __has_builtin(__builtin_amdgcn_exp2f)
  return __builtin_amdgcn_exp2f(x);
#else
  return exp2f(x);
#endif
}
__device__ __forceinline__ float gelu_tanh(float x) {
  float u = 0.7978845608028654f * (x + 0.044715f * x * x * x);
  // exp(-2|u|) = 2^(-2*log2e*|u|); |u| bounded by gemm outputs -> no denorm concern
  float e = fexp2(-2.8853900817779268f * fabsf(u));
  float t = (1.0f - e) / (1.0f + e);
  t = (u >= 0.0f) ? t : -t;
  return 0.5f * x * (1.0f + t);
}
__device__ __forceinline__ float silu_f(float v) {
  return v / (1.0f + fexp2(-1.4426950408889634f * v));
}
__device__ __forceinline__ f32x4 mfma16(bf16x8 a, bf16x8 b, f32x4 c) {
  return __builtin_amdgcn_mfma_f32_16x16x32_bf16(a, b, c, 0, 0, 0);
}

// ---------------- modulation: out = silu(vec) @ W + b ----------------
__global__ __launch_bounds__(256) void modulation_kernel(
    const float* __restrict__ vec,
    const float* __restrict__ w_o, const float* __restrict__ b_o,
    const float* __restrict__ w_c, const float* __restrict__ b_c,
    float* __restrict__ o_mod, float* __restrict__ c_mod) {
  __shared__ float sv[1024];
  __shared__ float red[256];
  const int tid = threadIdx.x;
  const bool isobs = blockIdx.x < 96;
  const float* w = isobs ? w_o : w_c;
  const float* b = isobs ? b_o : b_c;
  float* out = isobs ? o_mod : c_mod;
  const int jb = (isobs ? blockIdx.x : blockIdx.x - 96) * 64;
  const int col = tid & 63, sl = tid >> 6;
  for (int i = tid; i < 1024; i += 256) {
    sv[i] = silu_f(vec[i]);
  }
  __syncthreads();
  float acc = 0.0f;
  const int kb = sl * 256;
  for (int k = 0; k < 256; ++k)
    acc += sv[kb + k] * w[(size_t)(kb + k) * 6144 + jb + col];
  red[tid] = acc;
  __syncthreads();
  if (sl == 0)
    out[jb + col] = red[col] + red[col + 64] + red[col + 128] + red[col + 192] + b[jb + col];
}

// ------------- LayerNorm + (1+scale)*y + shift -> bf16 ; rows: cond first -------------
__global__ __launch_bounds__(256) void ln_mod_kernel(
    const float* __restrict__ xc, const float* __restrict__ xo,
    const float* __restrict__ modc, const float* __restrict__ modo,
    int mod_off, u16* __restrict__ out) {
  const int row = blockIdx.x, tid = threadIdx.x;
  const bool is_c = row < 1024;
  const float* x = is_c ? (xc + (size_t)row * 1024) : (xo + (size_t)(row - 1024) * 1024);
  const float* mod = (is_c ? modc : modo) + mod_off;
  float4 v = *(const float4*)(x + tid * 4);
  float s1 = v.x + v.y + v.z + v.w;
  float s2 = v.x * v.x + v.y * v.y + v.z * v.z + v.w * v.w;
#pragma unroll
  for (int m = 1; m < 64; m <<= 1) {
    s1 += __shfl_xor(s1, m);
    s2 += __shfl_xor(s2, m);
  }
  __shared__ float red[8];
  const int w = tid >> 6;
  if ((tid & 63) == 0) { red[w] = s1; red[4 + w] = s2; }
  __syncthreads();
  s1 = red[0] + red[1] + red[2] + red[3];
  s2 = red[4] + red[5] + red[6] + red[7];
  const float mean = s1 * (1.0f / 1024.0f);
  const float var = s2 * (1.0f / 1024.0f) - mean * mean;
  const float rstd = rsqrtf(var + 1e-6f);
  const int d = tid * 4;
  float vv[4] = {v.x, v.y, v.z, v.w};
  ushort4 ov;
  u16* po = (u16*)&ov;
#pragma unroll
  for (int i = 0; i < 4; ++i) {
    float y = (vv[i] - mean) * rstd;
    po[i] = f2bf((1.0f + mod[1024 + d + i]) * y + mod[d + i]);
  }
  *(ushort4*)(out + (size_t)row * 1024 + d) = ov;
}

// ---- same, bf16 input (x1 residual stream) ----
__global__ __launch_bounds__(256) void ln_mod_b_kernel(
    const u16* __restrict__ x,
    const float* __restrict__ modc, const float* __restrict__ modo,
    int mod_off, u16* __restrict__ out) {
  const int row = blockIdx.x, tid = threadIdx.x;
  const bool is_c = row < 1024;
  const float* mod = (is_c ? modc : modo) + mod_off;
  ushort4 rv = *(const ushort4*)(x + (size_t)row * 1024 + tid * 4);
  float vv[4] = {bf2f(rv.x), bf2f(rv.y), bf2f(rv.z), bf2f(rv.w)};
  float s1 = vv[0] + vv[1] + vv[2] + vv[3];
  float s2 = vv[0] * vv[0] + vv[1] * vv[1] + vv[2] * vv[2] + vv[3] * vv[3];
#pragma unroll
  for (int m = 1; m < 64; m <<= 1) {
    s1 += __shfl_xor(s1, m);
    s2 += __shfl_xor(s2, m);
  }
  __shared__ float red[8];
  const int w = tid >> 6;
  if ((tid & 63) == 0) { red[w] = s1; red[4 + w] = s2; }
  __syncthreads();
  s1 = red[0] + red[1] + red[2] + red[3];
  s2 = red[4] + red[5] + red[6] + red[7];
  const float mean = s1 * (1.0f / 1024.0f);
  const float var = s2 * (1.0f / 1024.0f) - mean * mean;
  const float rstd = rsqrtf(var + 1e-6f);
  const int d = tid * 4;
  ushort4 ov;
  u16* po = (u16*)&ov;
#pragma unroll
  for (int i = 0; i < 4; ++i) {
    float y = (vv[i] - mean) * rstd;
    po[i] = f2bf((1.0f + mod[1024 + d + i]) * y + mod[d + i]);
  }
  *(ushort4*)(out + (size_t)row * 1024 + d) = ov;
}

// ---- weight pre-cast+transpose: src f32 [K][N] -> dst bf16 [N][K] ----
__global__ __launch_bounds__(256) void transcast_kernel(
    const float* __restrict__ src_c, const float* __restrict__ src_o,
    u16* __restrict__ dst_c, u16* __restrict__ dst_o, int K, int N) {
  const float* src = blockIdx.z ? src_o : src_c;
  u16* dst = blockIdx.z ? dst_o : dst_c;
  const int n0 = blockIdx.x * 64, k0 = blockIdx.y * 64;
  __shared__ float s[64][65];
  const int tid = threadIdx.x;
  const int r = tid >> 4, c4 = (tid & 15) << 2;
#pragma unroll
  for (int p = 0; p < 4; ++p) {
    int kk = r + p * 16;
    float4 v = *(const float4*)(src + (size_t)(k0 + kk) * N + n0 + c4);
    s[kk][c4] = v.x; s[kk][c4 + 1] = v.y; s[kk][c4 + 2] = v.z; s[kk][c4 + 3] = v.w;
  }
  __syncthreads();
#pragma unroll
  for (int p = 0; p < 4; ++p) {
    int nr = r + p * 16;
    ushort4 ov;
    ov.x = f2bf(s[c4 + 0][nr]); ov.y = f2bf(s[c4 + 1][nr]);
    ov.z = f2bf(s[c4 + 2][nr]); ov.w = f2bf(s[c4 + 3][nr]);
    *(ushort4*)(dst + (size_t)(n0 + nr) * K + k0 + c4) = ov;
  }
}

// ---------------- GEMM m97-style: A bf16 [M][K] x BT bf16 [N][K], 128xBNx32 ----------------
// mode 0 epilogue writes V directly in vpack fragment layout (vtrans folded in).
template <int BN>
__global__ __launch_bounds__(256) void gemm_bf16(
    const u16* __restrict__ A, const u16* __restrict__ BTc, const u16* __restrict__ BTo,
    int N, int K, int mode,
    const float* __restrict__ bias_c, const float* __restrict__ bias_o,
    const float* __restrict__ gate_c, const float* __restrict__ gate_o,
    const float* __restrict__ x0_c, const float* __restrict__ x0_o,
    const u16* __restrict__ x1, void* __restrict__ outp,
    u16* __restrict__ oq, u16* __restrict__ ok, u16* __restrict__ ov) {
  constexpr int MI = (BN == 128) ? 4 : 2;
  __shared__ u16 As[128 * 32];   // unpadded: global_load_lds is lane-linear
  __shared__ u16 Bs[BN * 32];
  const int tid = threadIdx.x;
  const int m0 = blockIdx.y * 128, n0 = blockIdx.x * BN;
  const bool is_c = (m0 < 1024);
  const u16* __restrict__ BT = is_c ? BTc : BTo;
  const int w = tid >> 6, lane = tid & 63, quad = lane >> 4, ln = lane & 15;
  const int wm = (BN == 128) ? (w >> 1) * 64 : w * 32;
  const int wn = (BN == 128) ? (w & 1) * 64 : 0;
  f32x4 acc[MI][4] = {};
  const int nkt = K >> 5;
  for (int kt = 0; kt < nkt; ++kt) {
    __syncthreads();
    {
      int c = tid;
      GLOAD_LDS16(A + (size_t)(m0 + (c >> 2)) * K + kt * 32 + (c & 3) * 8, As + c * 8);
      c = tid + 256;
      GLOAD_LDS16(A + (size_t)(m0 + (c >> 2)) * K + kt * 32 + (c & 3) * 8, As + c * 8);
      c = tid;
      GLOAD_LDS16(BT + (size_t)(n0 + (c >> 2)) * K + kt * 32 + (c & 3) * 8, Bs + c * 8);
      if (BN == 128) {
        c = tid + 256;
        GLOAD_LDS16(BT + (size_t)(n0 + (c >> 2)) * K + kt * 32 + (c & 3) * 8, Bs + c * 8);
      }
    }
    __syncthreads();
    bf16x8 a[MI], b[4];
#pragma unroll
    for (int i = 0; i < MI; ++i)
      a[i] = *(const bf16x8*)(As + (wm + i * 16 + ln) * 32 + quad * 8);
#pragma unroll
    for (int j = 0; j < 4; ++j)
      b[j] = *(const bf16x8*)(Bs + (wn + j * 16 + ln) * 32 + quad * 8);
#pragma unroll
    for (int i = 0; i < MI; ++i)
#pragma unroll
      for (int j = 0; j < 4; ++j) acc[i][j] = mfma16(a[i], b[j], acc[i][j]);
  }
  const float* bias = is_c ? bias_c : bias_o;
  const float* gate = is_c ? gate_c : gate_o;
  const float* x0 = is_c ? x0_c : x0_o;
#pragma unroll
  for (int i = 0; i < MI; ++i) {
#pragma unroll
    for (int j = 0; j < 4; ++j) {
#pragma unroll
      for (int r = 0; r < 4; ++r) {
        const int row = m0 + wm + i * 16 + quad * 4 + r;
        const int col = n0 + wn + j * 16 + ln;
        const float v = acc[i][j][r];
        if (mode == 0) {
          const int which = col >> 10, hh = (col & 1023) >> 6, dd = col & 63;
          if (which == 2) {
            // V: straight to vpack fragment layout (see vpack comment at qkprep)
            const int cc = row >> 7, wv = (row >> 5) & 3, qd = (row >> 3) & 3, jr = row & 7;
            const int jd = dd >> 4, lnn = dd & 15;
            ov[(size_t)hh * 262144 +
               (size_t)(((((cc * 4 + wv) * 4 + jd) * 64) + qd * 16 + lnn) * 8 + jr)] = f2bf(v);
          } else {
            u16* dst = (which == 0) ? oq : ok;
            dst[((size_t)hh * 4096 + row) * 64 + dd] = f2bf(v);
          }
        } else if (mode == 1) {
          const float xv = is_c ? x0[(size_t)row * 1024 + col]
                                : x0[(size_t)(row - 1024) * 1024 + col];
          ((u16*)outp)[(size_t)row * 1024 + col] = f2bf(xv + gate[col] * (v + bias[col]));
        } else if (mode == 2) {
          ((u16*)outp)[(size_t)row * N + col] = f2bf(gelu_tanh(v + bias[col]));
        } else {
          const float res = bf2f(x1[(size_t)row * 1024 + col]);
          const float val = res + gate[col] * (v + bias[col]);
          const size_t oidx = (row < 1024)
              ? (size_t)3145728 + (size_t)row * 1024 + col
              : (size_t)(row - 1024) * 1024 + col;
          ((float*)outp)[oidx] = val;
        }
      }
    }
  }
}

// ---- in-place rmsnorm+rope on q; k additionally scattered to fragment-packed kpack ----
// kpack layout (per head, u16 units): unit = ((c*4 + w)*4 + kk*2 + hf); element
// [unit*512 + (quad*16+ln)*8 + j] = K[l = c*128 + w*32 + (ln>>2)*8 + kk*4 + (ln&3)]
//                                    [d = hf*32 + quad*8 + j]
// vpack layout (per head, u16 units): unit = ((c*4 + w)*4 + jd); element
// [unit*512 + (quad*16+ln)*8 + j] = V[key = c*128 + w*32 + quad*8 + j][d = jd*16 + ln]
// so attn's fragment loads are single coalesced lane-linear 1KB streams.
__global__ __launch_bounds__(256) void qkprep_kernel(
    const float* __restrict__ pe,
    const float* __restrict__ qs_c, const float* __restrict__ ks_c,
    const float* __restrict__ qs_o, const float* __restrict__ ks_o,
    u16* __restrict__ qraw, u16* __restrict__ kraw, u16* __restrict__ kpack) {
  const int l = blockIdx.x, tid = threadIdx.x;
  const bool is_c = l < 1024;
  const float* qs = is_c ? qs_c : qs_o;
  const float* ks = is_c ? ks_c : ks_o;
  const int head = tid >> 4, dd = (tid * 4) & 63;
  const size_t off = ((size_t)head * 4096 + l) * 64 + dd;
  const float* peb = pe + (size_t)l * 128 + (size_t)dd * 2;
  float4 pe0 = *(const float4*)(peb);
  float4 pe1 = *(const float4*)(peb + 4);
  {  // q (scaled into exp2-score domain), in-place
    ushort4 raw = *(const ushort4*)(qraw + off);
    float x0 = bf2f(raw.x), x1v = bf2f(raw.y), x2 = bf2f(raw.z), x3 = bf2f(raw.w);
    float ssq = x0 * x0 + x1v * x1v + x2 * x2 + x3 * x3;
#pragma unroll
    for (int m = 1; m < 16; m <<= 1) ssq += __shfl_xor(ssq, m);
    float rms = rsqrtf(ssq * (1.0f / 64.0f) + 1e-6f) * 0.18033688011112042f;
    float n0 = x0 * rms * qs[dd + 0], n1 = x1v * rms * qs[dd + 1];
    float n2 = x2 * rms * qs[dd + 2], n3 = x3 * rms * qs[dd + 3];
    ushort4 o;
    o.x = f2bf(pe0.x * n0 + pe0.y * n1);
    o.y = f2bf(pe0.z * n0 + pe0.w * n1);
    o.z = f2bf(pe1.x * n2 + pe1.y * n3);
    o.w = f2bf(pe1.z * n2 + pe1.w * n3);
    *(ushort4*)(qraw + off) = o;
  }
  {  // k -> fragment-packed kpack
    ushort4 raw = *(const ushort4*)(kraw + off);
    float x0 = bf2f(raw.x), x1v = bf2f(raw.y), x2 = bf2f(raw.z), x3 = bf2f(raw.w);
    float ssq = x0 * x0 + x1v * x1v + x2 * x2 + x3 * x3;
#pragma unroll
    for (int m = 1; m < 16; m <<= 1) ssq += __shfl_xor(ssq, m);
    float rms = rsqrtf(ssq * (1.0f / 64.0f) + 1e-6f);
    float n0 = x0 * rms * ks[dd + 0], n1 = x1v * rms * ks[dd + 1];
    float n2 = x2 * rms * ks[dd + 2], n3 = x3 * rms * ks[dd + 3];
    ushort4 o;
    o.x = f2bf(pe0.x * n0 + pe0.y * n1);
    o.y = f2bf(pe0.z * n0 + pe0.w * n1);
    o.z = f2bf(pe1.x * n2 + pe1.y * n3);
    o.w = f2bf(pe1.z * n2 + pe1.w * n3);
    const int cck = l >> 7, wvk = (l >> 5) & 3, rk = l & 31;
    const int kkk = (rk >> 2) & 1, lnk = ((rk >> 3) << 2) | (rk & 3);
    const int hfk = dd >> 5, qdk = (dd >> 3) & 3, j0k = dd & 7;
    u16* kdst = kpack + (size_t)head * 262144
        + (size_t)((((cck * 4 + wvk) * 4 + kkk * 2 + hfk) * 64 + qdk * 16 + lnk) * 8 + j0k);
    *(ushort4*)kdst = o;
  }
}

// ---- one pipelined chunk: coalesced fragment-stream prefetch, QK -> exp2 -> PV ----
// K fragments pre-permuted (kperm baked into kpack) so sT[kk][nq][r] at lane
// (quad,ln) holds P[nq*16+ln][key quad*8+kk*4+r]: the exact 8 keys PV's A-operand
// needs, in-lane. P never touches LDS; loads are lane-linear 1KB streams.
__device__ __forceinline__ void attn_chunk(
    int cn, const u16* kpB, const u16* vpB, int w, int lane,
    const bf16x8 (&bq)[4][2],
    bf16x8 (&akc)[2][2], bf16x8 (&bvc)[4],
    bf16x8 (&akn)[2][2], bf16x8 (&bvn)[4],
    f32x4 (&o)[4][4], float (&rs)[4]) {
  if (cn < 32) {   // prefetch chunk cn into the other buffer (covers ~1 chunk of compute)
    const int cb = (cn * 4 + w) * 4;
#pragma unroll
    for (int kk = 0; kk < 2; ++kk)
#pragma unroll
      for (int hf = 0; hf < 2; ++hf)
        akn[kk][hf] = *(const bf16x8*)(kpB + ((cb + kk * 2 + hf) << 9) + lane * 8);
#pragma unroll
    for (int jd = 0; jd < 4; ++jd)
      bvn[jd] = *(const bf16x8*)(vpB + ((cb + jd) << 9) + lane * 8);
  }
  f32x4 sT[2][4] = {};
#pragma unroll
  for (int kk = 0; kk < 2; ++kk)
#pragma unroll
    for (int nq = 0; nq < 4; ++nq) {
      sT[kk][nq] = mfma16(akc[kk][0], bq[nq][0], sT[kk][nq]);
      sT[kk][nq] = mfma16(akc[kk][1], bq[nq][1], sT[kk][nq]);
    }
  // raw v_exp_f32: scores pre-scaled by 0.125*log2e and bounded => no fixup needed
#pragma unroll
  for (int nq = 0; nq < 4; ++nq) {
    u32x4 pw;
#pragma unroll
    for (int kk = 0; kk < 2; ++kk) {
      float p0 = fexp2(sT[kk][nq][0]);
      float p1 = fexp2(sT[kk][nq][1]);
      float p2 = fexp2(sT[kk][nq][2]);
      float p3 = fexp2(sT[kk][nq][3]);
      rs[nq] += (p0 + p1) + (p2 + p3);
      pw[kk * 2 + 0] = pack_bf2(p0, p1);
      pw[kk * 2 + 1] = pack_bf2(p2, p3);
    }
    const bf16x8 ap = __builtin_bit_cast(bf16x8, pw);
#pragma unroll
    for (int jd = 0; jd < 4; ++jd)
      o[nq][jd] = mfma16(ap, bvc[jd], o[nq][jd]);
  }
}

// ------- flash attention v11: packed streams, LDS-free P, XCD head clustering -------
__global__ __launch_bounds__(256) void attn_kernel(
    const u16* __restrict__ qh, const u16* __restrict__ kp,
    const u16* __restrict__ vp, u16* __restrict__ attn) {
  constexpr int L = 4096;
  // XCD-aware remap: linear block L0 dispatches to XCD (L0 % 8). Give each head's
  // 64 blocks a fixed L0%8 so its 1MB kpack+vpack stays resident in ONE XCD's L2
  // (2 heads/XCD = 2MB < 4MiB). Measured: FETCH 69.7->12.4 MB (R9).
  const int L0 = blockIdx.y * 64 + blockIdx.x;
  const int h = (L0 & 7) * 2 + ((L0 >> 3) & 1);
  const int q0 = (L0 >> 4) * 64;
  const int tid = threadIdx.x, w = tid >> 6, lane = tid & 63;
  const int quad = lane >> 4, ln = lane & 15;
  // LDS used only by the epilogue cross-wave reduction (bufA/bufB/rs4)
  __shared__ __align__(16) char smem[35840];
  float* bufA = (float*)smem;
  float* bufB = bufA + 4352;
  float* rs4 = bufB + 4352;

  bf16x8 bq[4][2];
  const u16* qbase = qh + ((size_t)h * L + q0) * 64;
#pragma unroll
  for (int nq = 0; nq < 4; ++nq)
#pragma unroll
    for (int hf = 0; hf < 2; ++hf)
      bq[nq][hf] = *(const bf16x8*)(qbase + (nq * 16 + ln) * 64 + hf * 32 + quad * 8);

  f32x4 o[4][4] = {};
  float rs[4] = {0.f, 0.f, 0.f, 0.f};
  const u16* kpB = kp + (size_t)h * 262144;
  const u16* vpB = vp + (size_t)h * 262144;

  // double-buffered K/V register fragments; ping-pong via 2-unrolled loop
  bf16x8 akA[2][2], akB[2][2], bvA[4], bvB[4];
  {
    const int cb = w * 4;
#pragma unroll
    for (int kk = 0; kk < 2; ++kk)
#pragma unroll
      for (int hf = 0; hf < 2; ++hf)
        akA[kk][hf] = *(const bf16x8*)(kpB + ((cb + kk * 2 + hf) << 9) + lane * 8);
#pragma unroll
    for (int jd = 0; jd < 4; ++jd)
      bvA[jd] = *(const bf16x8*)(vpB + ((cb + jd) << 9) + lane * 8);
  }
  for (int c = 0; c < 32; c += 2) {
    attn_chunk(c + 1, kpB, vpB, w, lane, bq, akA, bvA, akB, bvB, o, rs);
    attn_chunk(c + 2, kpB, vpB, w, lane, bq, akB, bvB, akA, bvA, o, rs);
  }

  // ---- epilogue: cross-wave reduction of o and rs ----
  __syncthreads();
#pragma unroll
  for (int nq = 0; nq < 4; ++nq) {
    rs[nq] += __shfl_xor(rs[nq], 16);
    rs[nq] += __shfl_xor(rs[nq], 32);
  }
  if (quad == 0) {
#pragma unroll
    for (int nq = 0; nq < 4; ++nq) rs4[w * 64 + nq * 16 + ln] = rs[nq];
  }
  if (w == 1) {
#pragma unroll
    for (int nq = 0; nq < 4; ++nq)
#pragma unroll
      for (int jd = 0; jd < 4; ++jd)
        *(f32x4*)(bufA + (jd * 16 + ln) * 68 + nq * 16 + quad * 4) = o[nq][jd];
  }
  if (w == 3) {
#pragma unroll
    for (int nq = 0; nq < 4; ++nq)
#pragma unroll
      for (int jd = 0; jd < 4; ++jd)
        *(f32x4*)(bufB + (jd * 16 + ln) * 68 + nq * 16 + quad * 4) = o[nq][jd];
  }
  __syncthreads();
  if (w == 0) {
#pragma unroll
    for (int nq = 0; nq < 4; ++nq)
#pragma unroll
      for (int jd = 0; jd < 4; ++jd)
        o[nq][jd] += *(const f32x4*)(bufA + (jd * 16 + ln) * 68 + nq * 16 + quad * 4);
  }
  if (w == 2) {
#pragma unroll
    for (int nq = 0; nq < 4; ++nq)
#pragma unroll
      for (int jd = 0; jd < 4; ++jd)
        o[nq][jd] += *(const f32x4*)(bufB + (jd * 16 + ln) * 68 + nq * 16 + quad * 4);
  }
  __syncthreads();
  if (w == 2) {
#pragma unroll
    for (int nq = 0; nq < 4; ++nq)
#pragma unroll
      for (int jd = 0; jd < 4; ++jd)
        *(f32x4*)(bufA + (jd * 16 + ln) * 68 + nq * 16 + quad * 4) = o[nq][jd];
  }
  __syncthreads();
  if (w == 0) {
    float linv[4][4];
#pragma unroll
    for (int nq = 0; nq < 4; ++nq)
#pragma unroll
      for (int r = 0; r < 4; ++r) {
        const int qr = nq * 16 + quad * 4 + r;
        linv[nq][r] = 1.0f / (rs4[qr] + rs4[64 + qr] + rs4[128 + qr] + rs4[192 + qr]);
      }
#pragma unroll
    for (int nq = 0; nq < 4; ++nq)
#pragma unroll
      for (int jd = 0; jd < 4; ++jd) {
        f32x4 of = o[nq][jd];
        of += *(const f32x4*)(bufA + (jd * 16 + ln) * 68 + nq * 16 + quad * 4);
#pragma unroll
        for (int r = 0; r < 4; ++r) {
          const int row = q0 + nq * 16 + quad * 4 + r;
          attn[(size_t)row * 1024 + h * 64 + jd * 16 + ln] = f2bf(of[r] * linv[nq][r]);
        }
      }
  }
}

extern "C" void kernel_launch(void* const* d_in, const int* in_sizes, int n_in,
                              void* d_out, int out_size, void* d_ws, size_t ws_size,
                              hipStream_t stream) {
  (void)in_sizes; (void)n_in; (void)out_size; (void)ws_size;
  const float* obs         = (const float*)d_in[0];
  const float* cond        = (const float*)d_in[1];
  const float* vec         = (const float*)d_in[2];
  const float* pe          = (const float*)d_in[3];
  const float* obs_mod_w   = (const float*)d_in[4];
  const float* obs_mod_b   = (const float*)d_in[5];
  const float* obs_qkv_w   = (const float*)d_in[6];
  const float* obs_q_scale = (const float*)d_in[7];
  const float* obs_k_scale = (const float*)d_in[8];
  const float* obs_proj_w  = (const float*)d_in[9];
  const float* obs_proj_b  = (const float*)d_in[10];
  const float* obs_mlp_w1  = (const float*)d_in[11];
  const float* obs_mlp_b1  = (const float*)d_in[12];
  const float* obs_mlp_w2  = (const float*)d_in[13];
  const float* obs_mlp_b2  = (const float*)d_in[14];
  const float* cond_mod_w  = (const float*)d_in[15];
  const float* cond_mod_b  = (const float*)d_in[16];
  const float* cond_qkv_w  = (const float*)d_in[17];
  const float* cond_q_scale= (const float*)d_in[18];
  const float* cond_k_scale= (const float*)d_in[19];
  const float* cond_proj_w = (const float*)d_in[20];
  const float* cond_proj_b = (const float*)d_in[21];
  const float* cond_mlp_w1 = (const float*)d_in[22];
  const float* cond_mlp_b1 = (const float*)d_in[23];
  const float* cond_mlp_w2 = (const float*)d_in[24];
  const float* cond_mlp_b2 = (const float*)d_in[25];

  // Workspace (peak 64 MiB + 64 KiB — proven budget):
  //  [0,16M)   rotating bf16 weights: qkvT -> projT -> mlp1T -> mlp2T
  //  [16,24M)  xm -> x1(bf16)
  //  [24,32M)  qraw -> hm
  //  [32,40M)  kraw ─┐
  //  [40,48M)  kpack (ex-vraw slot; V now packed by gemm)  ├─> g (32 MiB after dead)
  //  [48,56M)  vpack ─┤
  //  [56,64M)  attn  ─┘
  char* ws = (char*)d_ws;
  float* o_mod = (float*)ws;
  float* c_mod = o_mod + 6144;
  char* base = ws + 65536;
  u16* qkvT_c  = (u16*)base;
  u16* qkvT_o  = (u16*)(base + 6291456);
  u16* projT_c = (u16*)base;
  u16* projT_o = (u16*)(base + 2097152);
  u16* mlp1T_c = (u16*)base;
  u16* mlp1T_o = (u16*)(base + 8388608);
  u16* mlp2T_c = (u16*)base;
  u16* mlp2T_o = (u16*)(base + 8388608);
  u16* xm   = (u16*)(base + 16777216);
  u16* x1   = (u16*)(base + 16777216);
  u16* qraw = (u16*)(base + 25165824);
  u16* hm   = (u16*)(base + 25165824);
  u16* kraw = (u16*)(base + 33554432);
  u16* kpack= (u16*)(base + 41943040);
  u16* vpack= (u16*)(base + 50331648);
  u16* attn = (u16*)(base + 58720256);
  u16* g    = (u16*)(base + 33554432);

  modulation_kernel<<<192, 256, 0, stream>>>(vec, obs_mod_w, obs_mod_b,
                                             cond_mod_w, cond_mod_b, o_mod, c_mod);
  ln_mod_kernel<<<4096, 256, 0, stream>>>(cond, obs, c_mod, o_mod, 0, xm);
  transcast_kernel<<<dim3(48, 16, 2), 256, 0, stream>>>(cond_qkv_w, obs_qkv_w,
                                                        qkvT_c, qkvT_o, 1024, 3072);
  gemm_bf16<128><<<dim3(24, 32), 256, 0, stream>>>(xm, qkvT_c, qkvT_o, 3072, 1024, 0,
      nullptr, nullptr, nullptr, nullptr, nullptr, nullptr, nullptr, nullptr,
      qraw, kraw, vpack);   // V written directly in vpack layout (vtrans folded)
  qkprep_kernel<<<4096, 256, 0, stream>>>(pe, cond_q_scale, cond_k_scale,
                                          obs_q_scale, obs_k_scale, qraw, kraw, kpack);
  attn_kernel<<<dim3(64, 16), 256, 0, stream>>>(qraw, kpack, vpack, attn);
  transcast_kernel<<<dim3(16, 16, 2), 256, 0, stream>>>(cond_proj_w, obs_proj_w,
                                                        projT_c, projT_o, 1024, 1024);
  gemm_bf16<64><<<dim3(16, 32), 256, 0, stream>>>(attn, projT_c, projT_o, 1024, 1024, 1,
      cond_proj_b, obs_proj_b, c_mod + 2048, o_mod + 2048, cond, obs,
      nullptr, (void*)x1, nullptr, nullptr, nullptr);
  ln_mod_b_kernel<<<4096, 256, 0, stream>>>(x1, c_mod, o_mod, 3072, hm);
  transcast_kernel<<<dim3(64, 16, 2), 256, 0, stream>>>(cond_mlp_w1, obs_mlp_w1,
                                                        mlp1T_c, mlp1T_o, 1024, 4096);
  gemm_bf16<128><<<dim3(32, 32), 256, 0, stream>>>(hm, mlp1T_c, mlp1T_o, 4096, 1024, 2,
      cond_mlp_b1, obs_mlp_b1, nullptr, nullptr, nullptr, nullptr,
      nullptr, (void*)g, nullptr, nullptr, nullptr);
  transcast_kernel<<<dim3(16, 64, 2), 256, 0, stream>>>(cond_mlp_w2, obs_mlp_w2,
                                                        mlp2T_c, mlp2T_o, 4096, 1024);
  gemm_bf16<64><<<dim3(16, 32), 256, 0, stream>>>(g, mlp2T_c, mlp2T_o, 1024, 4096, 3,
      cond_mlp_b2, obs_mlp_b2, c_mod + 5120, o_mod + 5120, nullptr, nullptr,
      x1, d_out, nullptr, nullptr, nullptr);
}

// Round 12
// 609.846 us; speedup vs baseline: 1.0719x; 1.0515x over previous
//
#include <hip/hip_runtime.h>

typedef unsigned short u16;
typedef __bf16 bf16x8 __attribute__((ext_vector_type(8)));
typedef __bf16 bf16x4 __attribute__((ext_vector_type(4)));
typedef float f32x4 __attribute__((ext_vector_type(4)));
typedef unsigned int u32x4 __attribute__((ext_vector_type(4)));

#define GLOAD_LDS16(g, l)                                                    \
  __builtin_amdgcn_global_load_lds(                                          \
      (const __attribute__((address_space(1))) void*)(g),                    \
      (__attribute__((address_space(3))) void*)(l), 16, 0, 0)

__device__ __forceinline__ u16 f2bf(float f) {
  unsigned int u = __float_as_uint(f);
  u += 0x7fffu + ((u >> 16) & 1u);   // RNE
  return (u16)(u >> 16);
}
__device__ __forceinline__ float bf2f(u16 h) {
  return __uint_as_float(((unsigned int)h) << 16);
}
// pack two f32 -> two bf16 (truncation) in one u32: low = a, high = b
// v_perm_b32: single-op, bit-identical to (b & 0xffff0000) | (a >> 16).
__device__ __forceinline__ unsigned int pack_bf2(float a, float b) {
#if __has_builtin(__builtin_amdgcn_perm)
  return __builtin_amdgcn_perm(__float_as_uint(b), __float_as_uint(a), 0x07060302u);
#else
  return (__float_as_uint(b) & 0xffff0000u) | (__float_as_uint(a) >> 16);
#endif
}
// raw v_exp_f32 — skips OCML denorm fixup. Safe: all inputs bounded (see call sites).
__device__ __forceinline__ float fexp2(float x) {
#if __has_builtin(__builtin_amdgcn_exp2f)
  return __builtin_amdgcn_exp2f(x);
#else
  return exp2f(x);
#endif
}
__device__ __forceinline__ float gelu_tanh(float x) {
  float u = 0.7978845608028654f * (x + 0.044715f * x * x * x);
  // exp(-2|u|) = 2^(-2*log2e*|u|); |u| bounded by gemm outputs -> no denorm concern
  float e = fexp2(-2.8853900817779268f * fabsf(u));
  float t = (1.0f - e) / (1.0f + e);
  t = (u >= 0.0f) ? t : -t;
  return 0.5f * x * (1.0f + t);
}
__device__ __forceinline__ float silu_f(float v) {
  return v / (1.0f + fexp2(-1.4426950408889634f * v));
}
__device__ __forceinline__ f32x4 mfma16(bf16x8 a, bf16x8 b, f32x4 c) {
  return __builtin_amdgcn_mfma_f32_16x16x32_bf16(a, b, c, 0, 0, 0);
}

// ---------------- modulation: out = silu(vec) @ W + b ----------------
__global__ __launch_bounds__(256) void modulation_kernel(
    const float* __restrict__ vec,
    const float* __restrict__ w_o, const float* __restrict__ b_o,
    const float* __restrict__ w_c, const float* __restrict__ b_c,
    float* __restrict__ o_mod, float* __restrict__ c_mod) {
  __shared__ float sv[1024];
  __shared__ float red[256];
  const int tid = threadIdx.x;
  const bool isobs = blockIdx.x < 96;
  const float* w = isobs ? w_o : w_c;
  const float* b = isobs ? b_o : b_c;
  float* out = isobs ? o_mod : c_mod;
  const int jb = (isobs ? blockIdx.x : blockIdx.x - 96) * 64;
  const int col = tid & 63, sl = tid >> 6;
  for (int i = tid; i < 1024; i += 256) {
    sv[i] = silu_f(vec[i]);
  }
  __syncthreads();
  float acc = 0.0f;
  const int kb = sl * 256;
  for (int k = 0; k < 256; ++k)
    acc += sv[kb + k] * w[(size_t)(kb + k) * 6144 + jb + col];
  red[tid] = acc;
  __syncthreads();
  if (sl == 0)
    out[jb + col] = red[col] + red[col + 64] + red[col + 128] + red[col + 192] + b[jb + col];
}

// ------------- LayerNorm + (1+scale)*y + shift -> bf16 ; rows: cond first -------------
__global__ __launch_bounds__(256) void ln_mod_kernel(
    const float* __restrict__ xc, const float* __restrict__ xo,
    const float* __restrict__ modc, const float* __restrict__ modo,
    int mod_off, u16* __restrict__ out) {
  const int row = blockIdx.x, tid = threadIdx.x;
  const bool is_c = row < 1024;
  const float* x = is_c ? (xc + (size_t)row * 1024) : (xo + (size_t)(row - 1024) * 1024);
  const float* mod = (is_c ? modc : modo) + mod_off;
  float4 v = *(const float4*)(x + tid * 4);
  float s1 = v.x + v.y + v.z + v.w;
  float s2 = v.x * v.x + v.y * v.y + v.z * v.z + v.w * v.w;
#pragma unroll
  for (int m = 1; m < 64; m <<= 1) {
    s1 += __shfl_xor(s1, m);
    s2 += __shfl_xor(s2, m);
  }
  __shared__ float red[8];
  const int w = tid >> 6;
  if ((tid & 63) == 0) { red[w] = s1; red[4 + w] = s2; }
  __syncthreads();
  s1 = red[0] + red[1] + red[2] + red[3];
  s2 = red[4] + red[5] + red[6] + red[7];
  const float mean = s1 * (1.0f / 1024.0f);
  const float var = s2 * (1.0f / 1024.0f) - mean * mean;
  const float rstd = rsqrtf(var + 1e-6f);
  const int d = tid * 4;
  float vv[4] = {v.x, v.y, v.z, v.w};
  ushort4 ov;
  u16* po = (u16*)&ov;
#pragma unroll
  for (int i = 0; i < 4; ++i) {
    float y = (vv[i] - mean) * rstd;
    po[i] = f2bf((1.0f + mod[1024 + d + i]) * y + mod[d + i]);
  }
  *(ushort4*)(out + (size_t)row * 1024 + d) = ov;
}

// ---- same, bf16 input (x1 residual stream) ----
__global__ __launch_bounds__(256) void ln_mod_b_kernel(
    const u16* __restrict__ x,
    const float* __restrict__ modc, const float* __restrict__ modo,
    int mod_off, u16* __restrict__ out) {
  const int row = blockIdx.x, tid = threadIdx.x;
  const bool is_c = row < 1024;
  const float* mod = (is_c ? modc : modo) + mod_off;
  ushort4 rv = *(const ushort4*)(x + (size_t)row * 1024 + tid * 4);
  float vv[4] = {bf2f(rv.x), bf2f(rv.y), bf2f(rv.z), bf2f(rv.w)};
  float s1 = vv[0] + vv[1] + vv[2] + vv[3];
  float s2 = vv[0] * vv[0] + vv[1] * vv[1] + vv[2] * vv[2] + vv[3] * vv[3];
#pragma unroll
  for (int m = 1; m < 64; m <<= 1) {
    s1 += __shfl_xor(s1, m);
    s2 += __shfl_xor(s2, m);
  }
  __shared__ float red[8];
  const int w = tid >> 6;
  if ((tid & 63) == 0) { red[w] = s1; red[4 + w] = s2; }
  __syncthreads();
  s1 = red[0] + red[1] + red[2] + red[3];
  s2 = red[4] + red[5] + red[6] + red[7];
  const float mean = s1 * (1.0f / 1024.0f);
  const float var = s2 * (1.0f / 1024.0f) - mean * mean;
  const float rstd = rsqrtf(var + 1e-6f);
  const int d = tid * 4;
  ushort4 ov;
  u16* po = (u16*)&ov;
#pragma unroll
  for (int i = 0; i < 4; ++i) {
    float y = (vv[i] - mean) * rstd;
    po[i] = f2bf((1.0f + mod[1024 + d + i]) * y + mod[d + i]);
  }
  *(ushort4*)(out + (size_t)row * 1024 + d) = ov;
}

// ---- weight pre-cast+transpose: src f32 [K][N] -> dst bf16 [N][K] ----
__global__ __launch_bounds__(256) void transcast_kernel(
    const float* __restrict__ src_c, const float* __restrict__ src_o,
    u16* __restrict__ dst_c, u16* __restrict__ dst_o, int K, int N) {
  const float* src = blockIdx.z ? src_o : src_c;
  u16* dst = blockIdx.z ? dst_o : dst_c;
  const int n0 = blockIdx.x * 64, k0 = blockIdx.y * 64;
  __shared__ float s[64][65];
  const int tid = threadIdx.x;
  const int r = tid >> 4, c4 = (tid & 15) << 2;
#pragma unroll
  for (int p = 0; p < 4; ++p) {
    int kk = r + p * 16;
    float4 v = *(const float4*)(src + (size_t)(k0 + kk) * N + n0 + c4);
    s[kk][c4] = v.x; s[kk][c4 + 1] = v.y; s[kk][c4 + 2] = v.z; s[kk][c4 + 3] = v.w;
  }
  __syncthreads();
#pragma unroll
  for (int p = 0; p < 4; ++p) {
    int nr = r + p * 16;
    ushort4 ov;
    ov.x = f2bf(s[c4 + 0][nr]); ov.y = f2bf(s[c4 + 1][nr]);
    ov.z = f2bf(s[c4 + 2][nr]); ov.w = f2bf(s[c4 + 3][nr]);
    *(ushort4*)(dst + (size_t)(n0 + nr) * K + k0 + c4) = ov;
  }
}

// ---------------- GEMM m97-style: A bf16 [M][K] x BT bf16 [N][K] ----------------
// BN=128: 128x128 tile, BK=32 (proven 912TF-class structure).
// BN=64 : 128x64 tile, BK=64 — halves barrier count for the K-heavy proj/mlp2
//         GEMMs; per-acc k-order identical to BK=32 (bit-identical output).
template <int BN>
__global__ __launch_bounds__(256) void gemm_bf16(
    const u16* __restrict__ A, const u16* __restrict__ BTc, const u16* __restrict__ BTo,
    int N, int K, int mode,
    const float* __restrict__ bias_c, const float* __restrict__ bias_o,
    const float* __restrict__ gate_c, const float* __restrict__ gate_o,
    const float* __restrict__ x0_c, const float* __restrict__ x0_o,
    const u16* __restrict__ x1, void* __restrict__ outp,
    u16* __restrict__ oq, u16* __restrict__ ok, u16* __restrict__ ov) {
  constexpr int MI = (BN == 128) ? 4 : 2;
  constexpr int BK = (BN == 128) ? 32 : 64;
  __shared__ u16 As[128 * BK];   // unpadded: global_load_lds is lane-linear
  __shared__ u16 Bs[BN * BK];
  const int tid = threadIdx.x;
  const int m0 = blockIdx.y * 128, n0 = blockIdx.x * BN;
  const bool is_c = (m0 < 1024);
  const u16* __restrict__ BT = is_c ? BTc : BTo;
  const int w = tid >> 6, lane = tid & 63, quad = lane >> 4, ln = lane & 15;
  const int wm = (BN == 128) ? (w >> 1) * 64 : w * 32;
  const int wn = (BN == 128) ? (w & 1) * 64 : 0;
  f32x4 acc[MI][4] = {};
  const int nkt = K / BK;
  for (int kt = 0; kt < nkt; ++kt) {
    __syncthreads();
    if constexpr (BN == 128) {
      int c = tid;
      GLOAD_LDS16(A + (size_t)(m0 + (c >> 2)) * K + kt * 32 + (c & 3) * 8, As + c * 8);
      c = tid + 256;
      GLOAD_LDS16(A + (size_t)(m0 + (c >> 2)) * K + kt * 32 + (c & 3) * 8, As + c * 8);
      c = tid;
      GLOAD_LDS16(BT + (size_t)(n0 + (c >> 2)) * K + kt * 32 + (c & 3) * 8, Bs + c * 8);
      c = tid + 256;
      GLOAD_LDS16(BT + (size_t)(n0 + (c >> 2)) * K + kt * 32 + (c & 3) * 8, Bs + c * 8);
    } else {
      // As: 128x64 u16 = 1024 x 16B, 4 per thread; row = idx>>3, col8 = (idx&7)*8
#pragma unroll
      for (int it = 0; it < 4; ++it) {
        int idx = tid + it * 256;
        GLOAD_LDS16(A + (size_t)(m0 + (idx >> 3)) * K + kt * 64 + (idx & 7) * 8,
                    As + idx * 8);
      }
      // Bs: 64x64 u16 = 512 x 16B, 2 per thread
#pragma unroll
      for (int it = 0; it < 2; ++it) {
        int idx = tid + it * 256;
        GLOAD_LDS16(BT + (size_t)(n0 + (idx >> 3)) * K + kt * 64 + (idx & 7) * 8,
                    Bs + idx * 8);
      }
    }
    __syncthreads();
    if constexpr (BN == 128) {
      bf16x8 a[MI], b[4];
#pragma unroll
      for (int i = 0; i < MI; ++i)
        a[i] = *(const bf16x8*)(As + (wm + i * 16 + ln) * 32 + quad * 8);
#pragma unroll
      for (int j = 0; j < 4; ++j)
        b[j] = *(const bf16x8*)(Bs + (wn + j * 16 + ln) * 32 + quad * 8);
#pragma unroll
      for (int i = 0; i < MI; ++i)
#pragma unroll
        for (int j = 0; j < 4; ++j) acc[i][j] = mfma16(a[i], b[j], acc[i][j]);
    } else {
#pragma unroll
      for (int kk2 = 0; kk2 < 2; ++kk2) {   // k-order matches BK=32: bit-identical acc
        bf16x8 a[MI], b[4];
#pragma unroll
        for (int i = 0; i < MI; ++i)
          a[i] = *(const bf16x8*)(As + (wm + i * 16 + ln) * 64 + kk2 * 32 + quad * 8);
#pragma unroll
        for (int j = 0; j < 4; ++j)
          b[j] = *(const bf16x8*)(Bs + (j * 16 + ln) * 64 + kk2 * 32 + quad * 8);
#pragma unroll
        for (int i = 0; i < MI; ++i)
#pragma unroll
          for (int j = 0; j < 4; ++j) acc[i][j] = mfma16(a[i], b[j], acc[i][j]);
      }
    }
  }
  const float* bias = is_c ? bias_c : bias_o;
  const float* gate = is_c ? gate_c : gate_o;
  const float* x0 = is_c ? x0_c : x0_o;
#pragma unroll
  for (int i = 0; i < MI; ++i) {
#pragma unroll
    for (int j = 0; j < 4; ++j) {
#pragma unroll
      for (int r = 0; r < 4; ++r) {
        const int row = m0 + wm + i * 16 + quad * 4 + r;
        const int col = n0 + wn + j * 16 + ln;
        const float v = acc[i][j][r];
        if (mode == 0) {
          const int which = col >> 10, hh = (col & 1023) >> 6, dd = col & 63;
          u16* dst = (which == 0) ? oq : (which == 1) ? ok : ov;
          dst[((size_t)hh * 4096 + row) * 64 + dd] = f2bf(v);
        } else if (mode == 1) {
          const float xv = is_c ? x0[(size_t)row * 1024 + col]
                                : x0[(size_t)(row - 1024) * 1024 + col];
          ((u16*)outp)[(size_t)row * 1024 + col] = f2bf(xv + gate[col] * (v + bias[col]));
        } else if (mode == 2) {
          ((u16*)outp)[(size_t)row * N + col] = f2bf(gelu_tanh(v + bias[col]));
        } else {
          const float res = bf2f(x1[(size_t)row * 1024 + col]);
          const float val = res + gate[col] * (v + bias[col]);
          const size_t oidx = (row < 1024)
              ? (size_t)3145728 + (size_t)row * 1024 + col
              : (size_t)(row - 1024) * 1024 + col;
          ((float*)outp)[oidx] = val;
        }
      }
    }
  }
}

// ---- in-place rmsnorm+rope on q; k additionally scattered to fragment-packed kpack ----
// kpack layout (per head, u16 units): unit = ((c*4 + w)*4 + kk*2 + hf); element
// [unit*512 + (quad*16+ln)*8 + j] = K[l = c*128 + w*32 + (ln>>2)*8 + kk*4 + (ln&3)]
//                                    [d = hf*32 + quad*8 + j]
// so attn's A-fragment load is a single coalesced lane-linear 1KB stream.
__global__ __launch_bounds__(256) void qkprep_kernel(
    const float* __restrict__ pe,
    const float* __restrict__ qs_c, const float* __restrict__ ks_c,
    const float* __restrict__ qs_o, const float* __restrict__ ks_o,
    u16* __restrict__ qraw, u16* __restrict__ kraw, u16* __restrict__ kpack) {
  const int l = blockIdx.x, tid = threadIdx.x;
  const bool is_c = l < 1024;
  const float* qs = is_c ? qs_c : qs_o;
  const float* ks = is_c ? ks_c : ks_o;
  const int head = tid >> 4, dd = (tid * 4) & 63;
  const size_t off = ((size_t)head * 4096 + l) * 64 + dd;
  const float* peb = pe + (size_t)l * 128 + (size_t)dd * 2;
  float4 pe0 = *(const float4*)(peb);
  float4 pe1 = *(const float4*)(peb + 4);
  {  // q (scaled into exp2-score domain), in-place
    ushort4 raw = *(const ushort4*)(qraw + off);
    float x0 = bf2f(raw.x), x1v = bf2f(raw.y), x2 = bf2f(raw.z), x3 = bf2f(raw.w);
    float ssq = x0 * x0 + x1v * x1v + x2 * x2 + x3 * x3;
#pragma unroll
    for (int m = 1; m < 16; m <<= 1) ssq += __shfl_xor(ssq, m);
    float rms = rsqrtf(ssq * (1.0f / 64.0f) + 1e-6f) * 0.18033688011112042f;
    float n0 = x0 * rms * qs[dd + 0], n1 = x1v * rms * qs[dd + 1];
    float n2 = x2 * rms * qs[dd + 2], n3 = x3 * rms * qs[dd + 3];
    ushort4 o;
    o.x = f2bf(pe0.x * n0 + pe0.y * n1);
    o.y = f2bf(pe0.z * n0 + pe0.w * n1);
    o.z = f2bf(pe1.x * n2 + pe1.y * n3);
    o.w = f2bf(pe1.z * n2 + pe1.w * n3);
    *(ushort4*)(qraw + off) = o;
  }
  {  // k -> fragment-packed kpack
    ushort4 raw = *(const ushort4*)(kraw + off);
    float x0 = bf2f(raw.x), x1v = bf2f(raw.y), x2 = bf2f(raw.z), x3 = bf2f(raw.w);
    float ssq = x0 * x0 + x1v * x1v + x2 * x2 + x3 * x3;
#pragma unroll
    for (int m = 1; m < 16; m <<= 1) ssq += __shfl_xor(ssq, m);
    float rms = rsqrtf(ssq * (1.0f / 64.0f) + 1e-6f);
    float n0 = x0 * rms * ks[dd + 0], n1 = x1v * rms * ks[dd + 1];
    float n2 = x2 * rms * ks[dd + 2], n3 = x3 * rms * ks[dd + 3];
    ushort4 o;
    o.x = f2bf(pe0.x * n0 + pe0.y * n1);
    o.y = f2bf(pe0.z * n0 + pe0.w * n1);
    o.z = f2bf(pe1.x * n2 + pe1.y * n3);
    o.w = f2bf(pe1.z * n2 + pe1.w * n3);
    const int cck = l >> 7, wvk = (l >> 5) & 3, rk = l & 31;
    const int kkk = (rk >> 2) & 1, lnk = ((rk >> 3) << 2) | (rk & 3);
    const int hfk = dd >> 5, qdk = (dd >> 3) & 3, j0k = dd & 7;
    u16* kdst = kpack + (size_t)head * 262144
        + (size_t)((((cck * 4 + wvk) * 4 + kkk * 2 + hfk) * 64 + qdk * 16 + lnk) * 8 + j0k);
    *(ushort4*)kdst = o;
  }
}

// ---- V transpose+pack: vraw[h][l][d] -> vpack fragment stream ----
// vpack layout (per head, u16 units): unit = ((c*4 + w)*4 + jd); element
// [unit*512 + (quad*16+ln)*8 + j] = V[key = c*128 + w*32 + quad*8 + j][d = jd*16 + ln]
__global__ __launch_bounds__(256) void vtrans_kernel(
    const u16* __restrict__ vh, u16* __restrict__ vpack) {
  const int h = blockIdx.y, k0 = blockIdx.x * 64;
  __shared__ u16 s[64 * 66];
  const int tid = threadIdx.x;
#pragma unroll
  for (int st = 0; st < 2; ++st) {
    int c = tid + st * 256;
    int row = c >> 3, off = (c & 7) << 3;
    ushort4 v0 = *(const ushort4*)(vh + ((size_t)h * 4096 + k0 + row) * 64 + off);
    ushort4 v1 = *(const ushort4*)(vh + ((size_t)h * 4096 + k0 + row) * 64 + off + 4);
    u16* p = s + row * 66 + off;
    p[0] = v0.x; p[1] = v0.y; p[2] = v0.z; p[3] = v0.w;
    p[4] = v1.x; p[5] = v1.y; p[6] = v1.z; p[7] = v1.w;
  }
  __syncthreads();
#pragma unroll
  for (int st = 0; st < 2; ++st) {
    int c = tid + st * 256;
    int dd = c >> 3, kk = (c & 7) << 3;
    ushort4 a, b;
    a.x = s[(kk + 0) * 66 + dd]; a.y = s[(kk + 1) * 66 + dd];
    a.z = s[(kk + 2) * 66 + dd]; a.w = s[(kk + 3) * 66 + dd];
    b.x = s[(kk + 4) * 66 + dd]; b.y = s[(kk + 5) * 66 + dd];
    b.z = s[(kk + 6) * 66 + dd]; b.w = s[(kk + 7) * 66 + dd];
    const int K0 = k0 + kk;
    const int cc = K0 >> 7, wv = (K0 >> 5) & 3, qd = (K0 >> 3) & 3;
    const int jd = dd >> 4, lnn = dd & 15;
    u16* o = vpack + (size_t)h * 262144
        + (size_t)((((cc * 4 + wv) * 4 + jd) * 64 + qd * 16 + lnn) * 8);
    *(ushort4*)(o) = a;
    *(ushort4*)(o + 4) = b;
  }
}

// ---- one pipelined chunk: coalesced fragment-stream prefetch, QK -> exp2 -> PV ----
// K fragments pre-permuted (kperm baked into kpack) so sT[kk][nq][r] at lane
// (quad,ln) holds P[nq*16+ln][key quad*8+kk*4+r]: the exact 8 keys PV's A-operand
// needs, in-lane. P never touches LDS; loads are lane-linear 1KB streams.
__device__ __forceinline__ void attn_chunk(
    int cn, const u16* kpB, const u16* vpB, int w, int lane,
    const bf16x8 (&bq)[4][2],
    bf16x8 (&akc)[2][2], bf16x8 (&bvc)[4],
    bf16x8 (&akn)[2][2], bf16x8 (&bvn)[4],
    f32x4 (&o)[4][4], float (&rs)[4]) {
  if (cn < 32) {   // prefetch chunk cn into the other buffer (covers ~1 chunk of compute)
    const int cb = (cn * 4 + w) * 4;
#pragma unroll
    for (int kk = 0; kk < 2; ++kk)
#pragma unroll
      for (int hf = 0; hf < 2; ++hf)
        akn[kk][hf] = *(const bf16x8*)(kpB + ((cb + kk * 2 + hf) << 9) + lane * 8);
#pragma unroll
    for (int jd = 0; jd < 4; ++jd)
      bvn[jd] = *(const bf16x8*)(vpB + ((cb + jd) << 9) + lane * 8);
  }
  f32x4 sT[2][4] = {};
#pragma unroll
  for (int kk = 0; kk < 2; ++kk)
#pragma unroll
    for (int nq = 0; nq < 4; ++nq) {
      sT[kk][nq] = mfma16(akc[kk][0], bq[nq][0], sT[kk][nq]);
      sT[kk][nq] = mfma16(akc[kk][1], bq[nq][1], sT[kk][nq]);
    }
  // raw v_exp_f32: scores pre-scaled by 0.125*log2e and bounded => no fixup needed
#pragma unroll
  for (int nq = 0; nq < 4; ++nq) {
    u32x4 pw;
#pragma unroll
    for (int kk = 0; kk < 2; ++kk) {
      float p0 = fexp2(sT[kk][nq][0]);
      float p1 = fexp2(sT[kk][nq][1]);
      float p2 = fexp2(sT[kk][nq][2]);
      float p3 = fexp2(sT[kk][nq][3]);
      rs[nq] += (p0 + p1) + (p2 + p3);
      pw[kk * 2 + 0] = pack_bf2(p0, p1);
      pw[kk * 2 + 1] = pack_bf2(p2, p3);
    }
    const bf16x8 ap = __builtin_bit_cast(bf16x8, pw);
#pragma unroll
    for (int jd = 0; jd < 4; ++jd)
      o[nq][jd] = mfma16(ap, bvc[jd], o[nq][jd]);
  }
}

// ------- flash attention v11: packed streams, LDS-free P, XCD head clustering -------
__global__ __launch_bounds__(256) void attn_kernel(
    const u16* __restrict__ qh, const u16* __restrict__ kp,
    const u16* __restrict__ vp, u16* __restrict__ attn) {
  constexpr int L = 4096;
  // XCD-aware remap: linear block L0 dispatches to XCD (L0 % 8). Give each head's
  // 64 blocks a fixed L0%8 so its 1MB kpack+vpack stays resident in ONE XCD's L2
  // (2 heads/XCD = 2MB < 4MiB). Measured: FETCH 69.7->12.4 MB (R9).
  const int L0 = blockIdx.y * 64 + blockIdx.x;
  const int h = (L0 & 7) * 2 + ((L0 >> 3) & 1);
  const int q0 = (L0 >> 4) * 64;
  const int tid = threadIdx.x, w = tid >> 6, lane = tid & 63;
  const int quad = lane >> 4, ln = lane & 15;
  // LDS used only by the epilogue cross-wave reduction (bufA/bufB/rs4)
  __shared__ __align__(16) char smem[35840];
  float* bufA = (float*)smem;
  float* bufB = bufA + 4352;
  float* rs4 = bufB + 4352;

  bf16x8 bq[4][2];
  const u16* qbase = qh + ((size_t)h * L + q0) * 64;
#pragma unroll
  for (int nq = 0; nq < 4; ++nq)
#pragma unroll
    for (int hf = 0; hf < 2; ++hf)
      bq[nq][hf] = *(const bf16x8*)(qbase + (nq * 16 + ln) * 64 + hf * 32 + quad * 8);

  f32x4 o[4][4] = {};
  float rs[4] = {0.f, 0.f, 0.f, 0.f};
  const u16* kpB = kp + (size_t)h * 262144;
  const u16* vpB = vp + (size_t)h * 262144;

  // double-buffered K/V register fragments; ping-pong via 2-unrolled loop
  bf16x8 akA[2][2], akB[2][2], bvA[4], bvB[4];
  {
    const int cb = w * 4;
#pragma unroll
    for (int kk = 0; kk < 2; ++kk)
#pragma unroll
      for (int hf = 0; hf < 2; ++hf)
        akA[kk][hf] = *(const bf16x8*)(kpB + ((cb + kk * 2 + hf) << 9) + lane * 8);
#pragma unroll
    for (int jd = 0; jd < 4; ++jd)
      bvA[jd] = *(const bf16x8*)(vpB + ((cb + jd) << 9) + lane * 8);
  }
  for (int c = 0; c < 32; c += 2) {
    attn_chunk(c + 1, kpB, vpB, w, lane, bq, akA, bvA, akB, bvB, o, rs);
    attn_chunk(c + 2, kpB, vpB, w, lane, bq, akB, bvB, akA, bvA, o, rs);
  }

  // ---- epilogue: cross-wave reduction of o and rs ----
  __syncthreads();
#pragma unroll
  for (int nq = 0; nq < 4; ++nq) {
    rs[nq] += __shfl_xor(rs[nq], 16);
    rs[nq] += __shfl_xor(rs[nq], 32);
  }
  if (quad == 0) {
#pragma unroll
    for (int nq = 0; nq < 4; ++nq) rs4[w * 64 + nq * 16 + ln] = rs[nq];
  }
  if (w == 1) {
#pragma unroll
    for (int nq = 0; nq < 4; ++nq)
#pragma unroll
      for (int jd = 0; jd < 4; ++jd)
        *(f32x4*)(bufA + (jd * 16 + ln) * 68 + nq * 16 + quad * 4) = o[nq][jd];
  }
  if (w == 3) {
#pragma unroll
    for (int nq = 0; nq < 4; ++nq)
#pragma unroll
      for (int jd = 0; jd < 4; ++jd)
        *(f32x4*)(bufB + (jd * 16 + ln) * 68 + nq * 16 + quad * 4) = o[nq][jd];
  }
  __syncthreads();
  if (w == 0) {
#pragma unroll
    for (int nq = 0; nq < 4; ++nq)
#pragma unroll
      for (int jd = 0; jd < 4; ++jd)
        o[nq][jd] += *(const f32x4*)(bufA + (jd * 16 + ln) * 68 + nq * 16 + quad * 4);
  }
  if (w == 2) {
#pragma unroll
    for (int nq = 0; nq < 4; ++nq)
#pragma unroll
      for (int jd = 0; jd < 4; ++jd)
        o[nq][jd] += *(const f32x4*)(bufB + (jd * 16 + ln) * 68 + nq * 16 + quad * 4);
  }
  __syncthreads();
  if (w == 2) {
#pragma unroll
    for (int nq = 0; nq < 4; ++nq)
#pragma unroll
      for (int jd = 0; jd < 4; ++jd)
        *(f32x4*)(bufA + (jd * 16 + ln) * 68 + nq * 16 + quad * 4) = o[nq][jd];
  }
  __syncthreads();
  if (w == 0) {
    float linv[4][4];
#pragma unroll
    for (int nq = 0; nq < 4; ++nq)
#pragma unroll
      for (int r = 0; r < 4; ++r) {
        const int qr = nq * 16 + quad * 4 + r;
        linv[nq][r] = 1.0f / (rs4[qr] + rs4[64 + qr] + rs4[128 + qr] + rs4[192 + qr]);
      }
#pragma unroll
    for (int nq = 0; nq < 4; ++nq)
#pragma unroll
      for (int jd = 0; jd < 4; ++jd) {
        f32x4 of = o[nq][jd];
        of += *(const f32x4*)(bufA + (jd * 16 + ln) * 68 + nq * 16 + quad * 4);
#pragma unroll
        for (int r = 0; r < 4; ++r) {
          const int row = q0 + nq * 16 + quad * 4 + r;
          attn[(size_t)row * 1024 + h * 64 + jd * 16 + ln] = f2bf(of[r] * linv[nq][r]);
        }
      }
  }
}

extern "C" void kernel_launch(void* const* d_in, const int* in_sizes, int n_in,
                              void* d_out, int out_size, void* d_ws, size_t ws_size,
                              hipStream_t stream) {
  (void)in_sizes; (void)n_in; (void)out_size; (void)ws_size;
  const float* obs         = (const float*)d_in[0];
  const float* cond        = (const float*)d_in[1];
  const float* vec         = (const float*)d_in[2];
  const float* pe          = (const float*)d_in[3];
  const float* obs_mod_w   = (const float*)d_in[4];
  const float* obs_mod_b   = (const float*)d_in[5];
  const float* obs_qkv_w   = (const float*)d_in[6];
  const float* obs_q_scale = (const float*)d_in[7];
  const float* obs_k_scale = (const float*)d_in[8];
  const float* obs_proj_w  = (const float*)d_in[9];
  const float* obs_proj_b  = (const float*)d_in[10];
  const float* obs_mlp_w1  = (const float*)d_in[11];
  const float* obs_mlp_b1  = (const float*)d_in[12];
  const float* obs_mlp_w2  = (const float*)d_in[13];
  const float* obs_mlp_b2  = (const float*)d_in[14];
  const float* cond_mod_w  = (const float*)d_in[15];
  const float* cond_mod_b  = (const float*)d_in[16];
  const float* cond_qkv_w  = (const float*)d_in[17];
  const float* cond_q_scale= (const float*)d_in[18];
  const float* cond_k_scale= (const float*)d_in[19];
  const float* cond_proj_w = (const float*)d_in[20];
  const float* cond_proj_b = (const float*)d_in[21];
  const float* cond_mlp_w1 = (const float*)d_in[22];
  const float* cond_mlp_b1 = (const float*)d_in[23];
  const float* cond_mlp_w2 = (const float*)d_in[24];
  const float* cond_mlp_b2 = (const float*)d_in[25];

  // Workspace (peak 64 MiB + 64 KiB — proven budget):
  //  [0,16M)   rotating bf16 weights: qkvT -> projT -> mlp1T -> mlp2T
  //  [16,24M)  xm -> x1(bf16)
  //  [24,32M)  qraw -> hm
  //  [32,40M)  kraw ─┐
  //  [40,48M)  vraw -> kpack (vraw dead after vtrans)  ├─> g (32 MiB after all dead)
  //  [48,56M)  vpack ─┤
  //  [56,64M)  attn  ─┘
  char* ws = (char*)d_ws;
  float* o_mod = (float*)ws;
  float* c_mod = o_mod + 6144;
  char* base = ws + 65536;
  u16* qkvT_c  = (u16*)base;
  u16* qkvT_o  = (u16*)(base + 6291456);
  u16* projT_c = (u16*)base;
  u16* projT_o = (u16*)(base + 2097152);
  u16* mlp1T_c = (u16*)base;
  u16* mlp1T_o = (u16*)(base + 8388608);
  u16* mlp2T_c = (u16*)base;
  u16* mlp2T_o = (u16*)(base + 8388608);
  u16* xm   = (u16*)(base + 16777216);
  u16* x1   = (u16*)(base + 16777216);
  u16* qraw = (u16*)(base + 25165824);
  u16* hm   = (u16*)(base + 25165824);
  u16* kraw = (u16*)(base + 33554432);
  u16* vraw = (u16*)(base + 41943040);
  u16* kpack= (u16*)(base + 41943040);   // aliases vraw; written after vtrans consumes it
  u16* vpack= (u16*)(base + 50331648);
  u16* attn = (u16*)(base + 58720256);
  u16* g    = (u16*)(base + 33554432);

  modulation_kernel<<<192, 256, 0, stream>>>(vec, obs_mod_w, obs_mod_b,
                                             cond_mod_w, cond_mod_b, o_mod, c_mod);
  ln_mod_kernel<<<4096, 256, 0, stream>>>(cond, obs, c_mod, o_mod, 0, xm);
  transcast_kernel<<<dim3(48, 16, 2), 256, 0, stream>>>(cond_qkv_w, obs_qkv_w,
                                                        qkvT_c, qkvT_o, 1024, 3072);
  gemm_bf16<128><<<dim3(24, 32), 256, 0, stream>>>(xm, qkvT_c, qkvT_o, 3072, 1024, 0,
      nullptr, nullptr, nullptr, nullptr, nullptr, nullptr, nullptr, nullptr,
      qraw, kraw, vraw);
  vtrans_kernel<<<dim3(64, 16), 256, 0, stream>>>(vraw, vpack);   // before qkprep: frees vraw slot
  qkprep_kernel<<<4096, 256, 0, stream>>>(pe, cond_q_scale, cond_k_scale,
                                          obs_q_scale, obs_k_scale, qraw, kraw, kpack);
  attn_kernel<<<dim3(64, 16), 256, 0, stream>>>(qraw, kpack, vpack, attn);
  transcast_kernel<<<dim3(16, 16, 2), 256, 0, stream>>>(cond_proj_w, obs_proj_w,
                                                        projT_c, projT_o, 1024, 1024);
  gemm_bf16<64><<<dim3(16, 32), 256, 0, stream>>>(attn, projT_c, projT_o, 1024, 1024, 1,
      cond_proj_b, obs_proj_b, c_mod + 2048, o_mod + 2048, cond, obs,
      nullptr, (void*)x1, nullptr, nullptr, nullptr);
  ln_mod_b_kernel<<<4096, 256, 0, stream>>>(x1, c_mod, o_mod, 3072, hm);
  transcast_kernel<<<dim3(64, 16, 2), 256, 0, stream>>>(cond_mlp_w1, obs_mlp_w1,
                                                        mlp1T_c, mlp1T_o, 1024, 4096);
  gemm_bf16<128><<<dim3(32, 32), 256, 0, stream>>>(hm, mlp1T_c, mlp1T_o, 4096, 1024, 2,
      cond_mlp_b1, obs_mlp_b1, nullptr, nullptr, nullptr, nullptr,
      nullptr, (void*)g, nullptr, nullptr, nullptr);
  transcast_kernel<<<dim3(16, 64, 2), 256, 0, stream>>>(cond_mlp_w2, obs_mlp_w2,
                                                        mlp2T_c, mlp2T_o, 4096, 1024);
  gemm_bf16<64><<<dim3(16, 32), 256, 0, stream>>>(g, mlp2T_c, mlp2T_o, 1024, 4096, 3,
      cond_mlp_b2, obs_mlp_b2, c_mod + 5120, o_mod + 5120, nullptr, nullptr,
      x1, d_out, nullptr, nullptr, nullptr);
}